// Round 1
// baseline (4488.158 us; speedup 1.0000x reference)
//
#include <hip/hip_runtime.h>
#include <hip/hip_bf16.h>

#define N_FEATS_IN 128
#define N_HIDDEN   128
#define N_CLASSES  64

// ---------------------------------------------------------------------------
// degree: deg_out[src[e]] += 1 ; deg_in[dst[e]] += 1  (float counters)
// ---------------------------------------------------------------------------
__global__ __launch_bounds__(256) void degree_kernel(
    const int* __restrict__ src, const int* __restrict__ dst,
    float* __restrict__ deg_out, float* __restrict__ deg_in, int nE) {
    int e = blockIdx.x * blockDim.x + threadIdx.x;
    if (e >= nE) return;
    atomicAdd(&deg_out[src[e]], 1.0f);
    atomicAdd(&deg_in[dst[e]], 1.0f);
}

// in-place: d -> rsqrt(max(d,1))   over 2N contiguous floats
__global__ __launch_bounds__(256) void norm_kernel(float* __restrict__ deg, int n2) {
    int i = blockIdx.x * blockDim.x + threadIdx.x;
    if (i >= n2) return;
    deg[i] = rsqrtf(fmaxf(deg[i], 1.0f));
}

// ---------------------------------------------------------------------------
// Y[n,OC] = (X[n,128] @ W[128,OC]) * scale[n]
// block: 256 threads = 4 row-groups x 64 col-threads; 32 rows/block.
// W and X tile staged in LDS; x reads are wave-uniform broadcasts.
// ---------------------------------------------------------------------------
template <int OC>
__global__ __launch_bounds__(256) void gemm_scale_kernel(
    const float* __restrict__ X, const float* __restrict__ W,
    const float* __restrict__ scale, float* __restrict__ Y, int n) {
    constexpr int K = 128;
    constexpr int ROWS = 32;
    constexpr int CPT = OC / 64;  // cols per thread (2 for OC=128, 1 for OC=64)

    __shared__ float Wl[K * OC];
    __shared__ float Xs[ROWS][K];

    const int tid = threadIdx.x;

    // stage W (coalesced float4)
    for (int i = tid; i < K * OC / 4; i += 256)
        ((float4*)Wl)[i] = ((const float4*)W)[i];

    // stage X tile (coalesced float4)
    const int row0 = blockIdx.x * ROWS;
    for (int i = tid; i < ROWS * K / 4; i += 256)
        ((float4*)&Xs[0][0])[i] = ((const float4*)&X[(size_t)row0 * K])[i];

    __syncthreads();

    const int tx = tid & 63;   // lane  -> column group
    const int ty = tid >> 6;   // wave  -> row group (wave-uniform)

    float acc[8][CPT];
#pragma unroll
    for (int r = 0; r < 8; ++r)
#pragma unroll
        for (int c = 0; c < CPT; ++c) acc[r][c] = 0.0f;

#pragma unroll 4
    for (int k4 = 0; k4 < K / 4; ++k4) {
        float4 xr[8];
#pragma unroll
        for (int r = 0; r < 8; ++r)
            xr[r] = *(const float4*)&Xs[ty * 8 + r][k4 * 4];
#pragma unroll
        for (int j = 0; j < 4; ++j) {
            const int k = k4 * 4 + j;
            float w[CPT];
            if constexpr (CPT == 2) {
                float2 wv = *(const float2*)&Wl[k * OC + tx * 2];
                w[0] = wv.x; w[1] = wv.y;
            } else {
                w[0] = Wl[k * OC + tx];
            }
#pragma unroll
            for (int r = 0; r < 8; ++r) {
                const float xv = (j == 0) ? xr[r].x : (j == 1) ? xr[r].y
                               : (j == 2) ? xr[r].z : xr[r].w;
#pragma unroll
                for (int c = 0; c < CPT; ++c) acc[r][c] += xv * w[c];
            }
        }
    }

#pragma unroll
    for (int r = 0; r < 8; ++r) {
        const int row = row0 + ty * 8 + r;
        if (row >= n) continue;
        const float s = scale[row];
        if constexpr (CPT == 2) {
            float2 o; o.x = acc[r][0] * s; o.y = acc[r][1] * s;
            *(float2*)&Y[(size_t)row * OC + tx * 2] = o;
        } else {
            Y[(size_t)row * OC + tx] = acc[r][0] * s;
        }
    }
}

// ---------------------------------------------------------------------------
// scatter-add: agg[dst[e], :] += T[src[e], :]   (FEAT/4 threads per edge)
// ---------------------------------------------------------------------------
template <int FEAT>
__global__ __launch_bounds__(256) void scatter_add_kernel(
    const float* __restrict__ T, const int* __restrict__ src,
    const int* __restrict__ dst, float* __restrict__ agg, int nE) {
    constexpr int TPE = FEAT / 4;  // threads per edge
    const long long gid = (long long)blockIdx.x * blockDim.x + threadIdx.x;
    const int e = (int)(gid / TPE);
    if (e >= nE) return;
    const int c = (int)(gid % TPE) * 4;
    const int s = src[e];
    const int d = dst[e];
    const float4 v = *(const float4*)&T[(size_t)s * FEAT + c];
    float* p = &agg[(size_t)d * FEAT + c];
    atomicAdd(p + 0, v.x);
    atomicAdd(p + 1, v.y);
    atomicAdd(p + 2, v.z);
    atomicAdd(p + 3, v.w);
}

// ---------------------------------------------------------------------------
// epilogue: out = norm_dst[row] * agg + bias[col]   (optional relu)
// ---------------------------------------------------------------------------
template <int FEAT, bool RELU>
__global__ __launch_bounds__(256) void epilogue_kernel(
    const float* __restrict__ agg, const float* __restrict__ norm_dst,
    const float* __restrict__ bias, float* __restrict__ out, int n) {
    constexpr int F4 = FEAT / 4;
    const int i4 = blockIdx.x * blockDim.x + threadIdx.x;
    if (i4 >= n * F4) return;
    const int row = i4 / F4;
    const int c4 = (i4 % F4) * 4;
    const float nd = norm_dst[row];
    const float4 a = *(const float4*)&agg[(size_t)i4 * 4];
    const float4 b = *(const float4*)&bias[c4];
    float4 r;
    r.x = a.x * nd + b.x;
    r.y = a.y * nd + b.y;
    r.z = a.z * nd + b.z;
    r.w = a.w * nd + b.w;
    if constexpr (RELU) {
        r.x = fmaxf(r.x, 0.0f); r.y = fmaxf(r.y, 0.0f);
        r.z = fmaxf(r.z, 0.0f); r.w = fmaxf(r.w, 0.0f);
    }
    *(float4*)&out[(size_t)i4 * 4] = r;
}

extern "C" void kernel_launch(void* const* d_in, const int* in_sizes, int n_in,
                              void* d_out, int out_size, void* d_ws, size_t ws_size,
                              hipStream_t stream) {
    const float* x   = (const float*)d_in[0];   // [N,128]
    const int*   src = (const int*)d_in[1];     // [E]
    const int*   dst = (const int*)d_in[2];     // [E]
    const float* W1  = (const float*)d_in[3];   // [128,128]
    const float* b1  = (const float*)d_in[4];   // [128]
    const float* W2  = (const float*)d_in[5];   // [128,64]
    const float* b2  = (const float*)d_in[6];   // [64]
    float* out = (float*)d_out;

    const int N  = in_sizes[0] / N_FEATS_IN;    // 100000
    const int E  = in_sizes[1];                 // 1600000

    // workspace layout (floats):
    //  [0,N)        norm_src (deg_out)
    //  [N,2N)       norm_dst (deg_in)
    //  [2N,130N)    bufA: t1 then h1         (N x 128)
    //  [130N,258N)  bufB: agg1               (N x 128)
    //  [258N,322N)  bufC: t2                 (N x 64)
    //  [322N,386N)  bufD: agg2               (N x 64)
    float* ws = (float*)d_ws;
    float* norm_src = ws;
    float* norm_dst = ws + (size_t)N;
    float* bufA = ws + (size_t)2 * N;
    float* bufB = bufA + (size_t)N * 128;
    float* bufC = bufB + (size_t)N * 128;
    float* bufD = bufC + (size_t)N * 64;

    // zero degree counters + accumulators
    hipMemsetAsync(norm_src, 0, (size_t)2 * N * sizeof(float), stream);
    hipMemsetAsync(bufB, 0, (size_t)N * 128 * sizeof(float), stream);
    hipMemsetAsync(bufD, 0, (size_t)N * 64 * sizeof(float), stream);

    // degrees -> norms
    degree_kernel<<<(E + 255) / 256, 256, 0, stream>>>(src, dst, norm_src, norm_dst, E);
    norm_kernel<<<(2 * N + 255) / 256, 256, 0, stream>>>(norm_src, 2 * N);

    // layer 1: t1 = (x @ W1) * norm_src
    gemm_scale_kernel<128><<<(N + 31) / 32, 256, 0, stream>>>(x, W1, norm_src, bufA, N);
    // agg1[dst] += t1[src]
    {
        const long long threads = (long long)E * 32;
        scatter_add_kernel<128><<<(int)((threads + 255) / 256), 256, 0, stream>>>(
            bufA, src, dst, bufB, E);
    }
    // h1 = relu(norm_dst * agg1 + b1)  (into bufA, t1 is dead)
    epilogue_kernel<128, true><<<(N * 32 + 255) / 256, 256, 0, stream>>>(
        bufB, norm_dst, b1, bufA, N);

    // layer 2: t2 = (h1 @ W2) * norm_src
    gemm_scale_kernel<64><<<(N + 31) / 32, 256, 0, stream>>>(bufA, W2, norm_src, bufC, N);
    // agg2[dst] += t2[src]
    {
        const long long threads = (long long)E * 16;
        scatter_add_kernel<64><<<(int)((threads + 255) / 256), 256, 0, stream>>>(
            bufC, src, dst, bufD, E);
    }
    // out = norm_dst * agg2 + b2
    epilogue_kernel<64, false><<<(N * 16 + 255) / 256, 256, 0, stream>>>(
        bufD, norm_dst, b2, out, N);
}

// Round 2
// 770.709 us; speedup vs baseline: 5.8234x; 5.8234x over previous
//
#include <hip/hip_runtime.h>
#include <hip/hip_bf16.h>

#define N_FEATS_IN 128

// ---------------------------------------------------------------------------
// int degree histogram: deg_out[src[e]]++ ; deg_in[dst[e]]++
// ---------------------------------------------------------------------------
__global__ __launch_bounds__(256) void degree_kernel(
    const int* __restrict__ src, const int* __restrict__ dst,
    int* __restrict__ deg_out, int* __restrict__ deg_in, int nE) {
    int e = blockIdx.x * blockDim.x + threadIdx.x;
    if (e >= nE) return;
    atomicAdd(&deg_out[src[e]], 1);
    atomicAdd(&deg_in[dst[e]], 1);
}

// norm[i] = rsqrt(max(deg[i],1)) over 2N contiguous ints -> floats
__global__ __launch_bounds__(256) void norm_kernel(
    const int* __restrict__ deg, float* __restrict__ norm, int n2) {
    int i = blockIdx.x * blockDim.x + threadIdx.x;
    if (i >= n2) return;
    norm[i] = rsqrtf(fmaxf((float)deg[i], 1.0f));
}

// ---------------------------------------------------------------------------
// single-block exclusive scan of deg_in[0..n) -> row_ptr[0..n], row_ptr[n]=E
// 1024 threads x 4 elems/iter = 4096 per pass; Hillis-Steele in LDS.
// ---------------------------------------------------------------------------
__global__ __launch_bounds__(1024) void scan_kernel(
    const int* __restrict__ deg, int* __restrict__ row_ptr, int n) {
    __shared__ int sh[1024];
    const int t = threadIdx.x;
    int carry = 0;
    for (int base = 0; base < n; base += 4096) {
        const int i0 = base + t * 4;
        const int v0 = (i0 + 0 < n) ? deg[i0 + 0] : 0;
        const int v1 = (i0 + 1 < n) ? deg[i0 + 1] : 0;
        const int v2 = (i0 + 2 < n) ? deg[i0 + 2] : 0;
        const int v3 = (i0 + 3 < n) ? deg[i0 + 3] : 0;
        sh[t] = v0 + v1 + v2 + v3;
        __syncthreads();
        for (int off = 1; off < 1024; off <<= 1) {
            const int tmp = (t >= off) ? sh[t - off] : 0;
            __syncthreads();
            sh[t] += tmp;
            __syncthreads();
        }
        const int excl = carry + ((t > 0) ? sh[t - 1] : 0);
        if (i0 + 0 < n) row_ptr[i0 + 0] = excl;
        if (i0 + 1 < n) row_ptr[i0 + 1] = excl + v0;
        if (i0 + 2 < n) row_ptr[i0 + 2] = excl + v0 + v1;
        if (i0 + 3 < n) row_ptr[i0 + 3] = excl + v0 + v1 + v2;
        carry += sh[1023];
        __syncthreads();  // protect sh before next pass overwrites
    }
    if (t == 0) row_ptr[n] = carry;
}

// ---------------------------------------------------------------------------
// bucket fill: edge_src[row_ptr[dst[e]] + cursor[dst[e]]++] = src[e]
// ---------------------------------------------------------------------------
__global__ __launch_bounds__(256) void bucket_kernel(
    const int* __restrict__ src, const int* __restrict__ dst,
    const int* __restrict__ row_ptr, int* __restrict__ cursor,
    int* __restrict__ edge_src, int nE) {
    int e = blockIdx.x * blockDim.x + threadIdx.x;
    if (e >= nE) return;
    const int d = dst[e];
    const int pos = row_ptr[d] + atomicAdd(&cursor[d], 1);
    edge_src[pos] = src[e];
}

// ---------------------------------------------------------------------------
// Y[n,OC] = (X[n,128] @ W[128,OC]) * scale[n]
// block: 256 threads = 4 row-groups x 64 col-threads; 32 rows/block.
// ---------------------------------------------------------------------------
template <int OC>
__global__ __launch_bounds__(256) void gemm_scale_kernel(
    const float* __restrict__ X, const float* __restrict__ W,
    const float* __restrict__ scale, float* __restrict__ Y, int n) {
    constexpr int K = 128;
    constexpr int ROWS = 32;
    constexpr int CPT = OC / 64;  // cols per thread

    __shared__ float Wl[K * OC];
    __shared__ float Xs[ROWS][K];

    const int tid = threadIdx.x;
    for (int i = tid; i < K * OC / 4; i += 256)
        ((float4*)Wl)[i] = ((const float4*)W)[i];
    const int row0 = blockIdx.x * ROWS;
    for (int i = tid; i < ROWS * K / 4; i += 256)
        ((float4*)&Xs[0][0])[i] = ((const float4*)&X[(size_t)row0 * K])[i];
    __syncthreads();

    const int tx = tid & 63;
    const int ty = tid >> 6;

    float acc[8][CPT];
#pragma unroll
    for (int r = 0; r < 8; ++r)
#pragma unroll
        for (int c = 0; c < CPT; ++c) acc[r][c] = 0.0f;

#pragma unroll 4
    for (int k4 = 0; k4 < K / 4; ++k4) {
        float4 xr[8];
#pragma unroll
        for (int r = 0; r < 8; ++r)
            xr[r] = *(const float4*)&Xs[ty * 8 + r][k4 * 4];
#pragma unroll
        for (int j = 0; j < 4; ++j) {
            const int k = k4 * 4 + j;
            float w[CPT];
            if constexpr (CPT == 2) {
                float2 wv = *(const float2*)&Wl[k * OC + tx * 2];
                w[0] = wv.x; w[1] = wv.y;
            } else {
                w[0] = Wl[k * OC + tx];
            }
#pragma unroll
            for (int r = 0; r < 8; ++r) {
                const float xv = (j == 0) ? xr[r].x : (j == 1) ? xr[r].y
                               : (j == 2) ? xr[r].z : xr[r].w;
#pragma unroll
                for (int c = 0; c < CPT; ++c) acc[r][c] += xv * w[c];
            }
        }
    }

#pragma unroll
    for (int r = 0; r < 8; ++r) {
        const int row = row0 + ty * 8 + r;
        if (row >= n) continue;
        const float s = scale[row];
        if constexpr (CPT == 2) {
            float2 o; o.x = acc[r][0] * s; o.y = acc[r][1] * s;
            *(float2*)&Y[(size_t)row * OC + tx * 2] = o;
        } else {
            Y[(size_t)row * OC + tx] = acc[r][0] * s;
        }
    }
}

// ---------------------------------------------------------------------------
// pull aggregation + fused epilogue:
//   out[node,:] = norm_dst[node] * sum_{j in [row_ptr[node],row_ptr[node+1])}
//                 T[edge_src[j],:]  + bias     (optional relu)
// FEAT/4 threads per node, float4 lanes; edge loop 2x unrolled for MLP.
// ---------------------------------------------------------------------------
template <int FEAT, bool RELU>
__global__ __launch_bounds__(256) void gather_agg_kernel(
    const float* __restrict__ T, const int* __restrict__ row_ptr,
    const int* __restrict__ edge_src, const float* __restrict__ norm_dst,
    const float* __restrict__ bias, float* __restrict__ out, int n) {
    constexpr int TPN = FEAT / 4;    // threads per node (32 / 16)
    constexpr int NPB = 256 / TPN;   // nodes per block  (8 / 16)
    const int node = blockIdx.x * NPB + threadIdx.x / TPN;
    const int f4 = threadIdx.x % TPN;
    if (node >= n) return;
    const int beg = row_ptr[node];
    const int end = row_ptr[node + 1];

    float4 acc = make_float4(0.f, 0.f, 0.f, 0.f);
    int j = beg;
    for (; j + 1 < end; j += 2) {
        const int s0 = edge_src[j];
        const int s1 = edge_src[j + 1];
        const float4 a = *(const float4*)&T[(size_t)s0 * FEAT + f4 * 4];
        const float4 b = *(const float4*)&T[(size_t)s1 * FEAT + f4 * 4];
        acc.x += a.x + b.x; acc.y += a.y + b.y;
        acc.z += a.z + b.z; acc.w += a.w + b.w;
    }
    if (j < end) {
        const int s0 = edge_src[j];
        const float4 a = *(const float4*)&T[(size_t)s0 * FEAT + f4 * 4];
        acc.x += a.x; acc.y += a.y; acc.z += a.z; acc.w += a.w;
    }

    const float nd = norm_dst[node];
    const float4 b = *(const float4*)&bias[f4 * 4];
    float4 r;
    r.x = acc.x * nd + b.x;
    r.y = acc.y * nd + b.y;
    r.z = acc.z * nd + b.z;
    r.w = acc.w * nd + b.w;
    if constexpr (RELU) {
        r.x = fmaxf(r.x, 0.f); r.y = fmaxf(r.y, 0.f);
        r.z = fmaxf(r.z, 0.f); r.w = fmaxf(r.w, 0.f);
    }
    *(float4*)&out[(size_t)node * FEAT + f4 * 4] = r;
}

extern "C" void kernel_launch(void* const* d_in, const int* in_sizes, int n_in,
                              void* d_out, int out_size, void* d_ws, size_t ws_size,
                              hipStream_t stream) {
    const float* x   = (const float*)d_in[0];   // [N,128]
    const int*   src = (const int*)d_in[1];     // [E]
    const int*   dst = (const int*)d_in[2];     // [E]
    const float* W1  = (const float*)d_in[3];   // [128,128]
    const float* b1  = (const float*)d_in[4];   // [128]
    const float* W2  = (const float*)d_in[5];   // [128,64]
    const float* b2  = (const float*)d_in[6];   // [64]
    float* out = (float*)d_out;

    const int N = in_sizes[0] / N_FEATS_IN;     // 100000
    const int E = in_sizes[1];                  // 1600000

    // workspace layout, 4-byte words, each region 16B-aligned
    auto align4 = [](size_t w) { return (w + 3) & ~(size_t)3; };
    char* base = (char*)d_ws;
    size_t off = 0;
    auto take = [&](size_t words) {
        char* p = base + off * 4;
        off = align4(off + words);
        return p;
    };
    int*   deg_out  = (int*)take(N);          // [N]  (deg_out, deg_in, cursor
    int*   deg_in   = (int*)take(N);          //       contiguous for one memset)
    int*   cursor   = (int*)take(N);
    int*   row_ptr  = (int*)take(N + 1);
    int*   edge_src = (int*)take(E);
    float* norms    = (float*)take(2 * (size_t)N);  // norm_src | norm_dst
    float* bufA     = (float*)take((size_t)N * 128);  // t1
    float* bufB     = (float*)take((size_t)N * 128);  // h1
    float* bufC     = (float*)take((size_t)N * 64);   // t2
    float* norm_src = norms;
    float* norm_dst = norms + N;

    // zero: deg_out, deg_in, cursor (contiguous 3N ints)
    hipMemsetAsync(deg_out, 0, (size_t)3 * N * sizeof(int), stream);

    // ---- CSR build ----
    degree_kernel<<<(E + 255) / 256, 256, 0, stream>>>(src, dst, deg_out, deg_in, E);
    norm_kernel<<<(2 * N + 255) / 256, 256, 0, stream>>>(deg_out, norms, 2 * N);
    scan_kernel<<<1, 1024, 0, stream>>>(deg_in, row_ptr, N);
    bucket_kernel<<<(E + 255) / 256, 256, 0, stream>>>(src, dst, row_ptr, cursor,
                                                       edge_src, E);

    // ---- layer 1 ----
    gemm_scale_kernel<128><<<(N + 31) / 32, 256, 0, stream>>>(x, W1, norm_src, bufA, N);
    gather_agg_kernel<128, true><<<(N + 7) / 8, 256, 0, stream>>>(
        bufA, row_ptr, edge_src, norm_dst, b1, bufB, N);

    // ---- layer 2 ----
    gemm_scale_kernel<64><<<(N + 31) / 32, 256, 0, stream>>>(bufB, W2, norm_src, bufC, N);
    gather_agg_kernel<64, false><<<(N + 15) / 16, 256, 0, stream>>>(
        bufC, row_ptr, edge_src, norm_dst, b2, out, N);
}

// Round 3
// 598.127 us; speedup vs baseline: 7.5037x; 1.2885x over previous
//
#include <hip/hip_runtime.h>
#include <hip/hip_bf16.h>

#define N_FEATS_IN 128

typedef _Float16 h8 __attribute__((ext_vector_type(8)));
typedef _Float16 h2 __attribute__((ext_vector_type(2)));
typedef float    f8v __attribute__((ext_vector_type(8)));

// ---------------------------------------------------------------------------
// int degree histogram: deg_out[src[e]]++ ; deg_in[dst[e]]++
// ---------------------------------------------------------------------------
__global__ __launch_bounds__(256) void degree_kernel(
    const int* __restrict__ src, const int* __restrict__ dst,
    int* __restrict__ deg_out, int* __restrict__ deg_in, int nE) {
    int e = blockIdx.x * blockDim.x + threadIdx.x;
    if (e >= nE) return;
    atomicAdd(&deg_out[src[e]], 1);
    atomicAdd(&deg_in[dst[e]], 1);
}

// norm[i] = rsqrt(max(deg[i],1)) over 2N contiguous ints -> floats
__global__ __launch_bounds__(256) void norm_kernel(
    const int* __restrict__ deg, float* __restrict__ norm, int n2) {
    int i = blockIdx.x * blockDim.x + threadIdx.x;
    if (i >= n2) return;
    norm[i] = rsqrtf(fmaxf((float)deg[i], 1.0f));
}

// ---------------------------------------------------------------------------
// 3-kernel exclusive scan of deg_in[0..n) -> row_ptr[0..n] (row_ptr[n]=E)
// scan1: per-block (1024 elems) local exclusive scan + block sums
// scan2: single block scans block sums (B <= 256), writes row_ptr[n]=total
// scan3: add block offsets
// ---------------------------------------------------------------------------
__global__ __launch_bounds__(256) void scan1_kernel(
    const int* __restrict__ deg, int* __restrict__ rp,
    int* __restrict__ bsum, int n) {
    __shared__ int ws[4];
    const int t = threadIdx.x;
    const int i0 = blockIdx.x * 1024 + t * 4;
    const int v0 = (i0 + 0 < n) ? deg[i0 + 0] : 0;
    const int v1 = (i0 + 1 < n) ? deg[i0 + 1] : 0;
    const int v2 = (i0 + 2 < n) ? deg[i0 + 2] : 0;
    const int v3 = (i0 + 3 < n) ? deg[i0 + 3] : 0;
    const int tsum = v0 + v1 + v2 + v3;
    const int lane = t & 63, wid = t >> 6;
    int inc = tsum;
    for (int off = 1; off < 64; off <<= 1) {
        int u = __shfl_up(inc, off, 64);
        if (lane >= off) inc += u;
    }
    if (lane == 63) ws[wid] = inc;
    __syncthreads();
    int woff = 0;
#pragma unroll
    for (int w = 0; w < 4; ++w) woff += (w < wid) ? ws[w] : 0;
    const int excl = woff + inc - tsum;
    if (i0 + 0 < n) rp[i0 + 0] = excl;
    if (i0 + 1 < n) rp[i0 + 1] = excl + v0;
    if (i0 + 2 < n) rp[i0 + 2] = excl + v0 + v1;
    if (i0 + 3 < n) rp[i0 + 3] = excl + v0 + v1 + v2;
    if (t == 255) bsum[blockIdx.x] = woff + inc;
}

__global__ __launch_bounds__(256) void scan2_kernel(
    const int* __restrict__ bsum, int* __restrict__ boff,
    int* __restrict__ rp, int B, int n) {
    __shared__ int ws[4];
    const int t = threadIdx.x;
    const int v = (t < B) ? bsum[t] : 0;
    const int lane = t & 63, wid = t >> 6;
    int inc = v;
    for (int off = 1; off < 64; off <<= 1) {
        int u = __shfl_up(inc, off, 64);
        if (lane >= off) inc += u;
    }
    if (lane == 63) ws[wid] = inc;
    __syncthreads();
    int woff = 0;
#pragma unroll
    for (int w = 0; w < 4; ++w) woff += (w < wid) ? ws[w] : 0;
    if (t < B) boff[t] = woff + inc - v;
    if (t == 255) rp[n] = woff + inc;  // grand total = E
}

__global__ __launch_bounds__(256) void scan3_kernel(
    int* __restrict__ rp, const int* __restrict__ boff, int n) {
    const int add = boff[blockIdx.x];
    const int i0 = blockIdx.x * 1024 + threadIdx.x * 4;
    if (i0 + 3 < n) {
        int4 v = *(int4*)&rp[i0];
        v.x += add; v.y += add; v.z += add; v.w += add;
        *(int4*)&rp[i0] = v;
    } else {
#pragma unroll
        for (int k = 0; k < 4; ++k)
            if (i0 + k < n) rp[i0 + k] += add;
    }
}

// ---------------------------------------------------------------------------
// bucket fill: edge_src[row_ptr[dst[e]] + cursor[dst[e]]++] = src[e]
// ---------------------------------------------------------------------------
__global__ __launch_bounds__(256) void bucket_kernel(
    const int* __restrict__ src, const int* __restrict__ dst,
    const int* __restrict__ row_ptr, int* __restrict__ cursor,
    int* __restrict__ edge_src, int nE) {
    int e = blockIdx.x * blockDim.x + threadIdx.x;
    if (e >= nE) return;
    const int d = dst[e];
    const int pos = row_ptr[d] + atomicAdd(&cursor[d], 1);
    edge_src[pos] = src[e];
}

// ---------------------------------------------------------------------------
// Y[n,OC] = (X[n,128] @ W[128,OC]) * scale[n],  Y stored as fp16.
// X is fp32 (XHALF=false) or fp16 (XHALF=true); compute fp32.
// block: 256 threads = 4 row-groups x 64 col-threads; 32 rows/block.
// ---------------------------------------------------------------------------
template <int OC, bool XHALF>
__global__ __launch_bounds__(256) void gemm_scale_kernel(
    const void* __restrict__ Xv, const float* __restrict__ W,
    const float* __restrict__ scale, _Float16* __restrict__ Y, int n) {
    constexpr int K = 128;
    constexpr int ROWS = 32;
    constexpr int CPT = OC / 64;  // cols per thread

    __shared__ float Wl[K * OC];
    __shared__ float Xs[ROWS][K];

    const int tid = threadIdx.x;
    for (int i = tid; i < K * OC / 4; i += 256)
        ((float4*)Wl)[i] = ((const float4*)W)[i];

    const int row0 = blockIdx.x * ROWS;
    if constexpr (XHALF) {
        const _Float16* X = (const _Float16*)Xv;
        for (int i = tid; i < ROWS * K / 8; i += 256) {
            h8 v = ((const h8*)&X[(size_t)row0 * K])[i];
            f8v f = __builtin_convertvector(v, f8v);
#pragma unroll
            for (int k = 0; k < 8; ++k) (&Xs[0][0])[i * 8 + k] = f[k];
        }
    } else {
        const float* X = (const float*)Xv;
        for (int i = tid; i < ROWS * K / 4; i += 256)
            ((float4*)&Xs[0][0])[i] = ((const float4*)&X[(size_t)row0 * K])[i];
    }
    __syncthreads();

    const int tx = tid & 63;
    const int ty = tid >> 6;

    float acc[8][CPT];
#pragma unroll
    for (int r = 0; r < 8; ++r)
#pragma unroll
        for (int c = 0; c < CPT; ++c) acc[r][c] = 0.0f;

#pragma unroll 4
    for (int k4 = 0; k4 < K / 4; ++k4) {
        float4 xr[8];
#pragma unroll
        for (int r = 0; r < 8; ++r)
            xr[r] = *(const float4*)&Xs[ty * 8 + r][k4 * 4];
#pragma unroll
        for (int j = 0; j < 4; ++j) {
            const int k = k4 * 4 + j;
            float w[CPT];
            if constexpr (CPT == 2) {
                float2 wv = *(const float2*)&Wl[k * OC + tx * 2];
                w[0] = wv.x; w[1] = wv.y;
            } else {
                w[0] = Wl[k * OC + tx];
            }
#pragma unroll
            for (int r = 0; r < 8; ++r) {
                const float xv = (j == 0) ? xr[r].x : (j == 1) ? xr[r].y
                               : (j == 2) ? xr[r].z : xr[r].w;
#pragma unroll
                for (int c = 0; c < CPT; ++c) acc[r][c] += xv * w[c];
            }
        }
    }

#pragma unroll
    for (int r = 0; r < 8; ++r) {
        const int row = row0 + ty * 8 + r;
        if (row >= n) continue;
        const float s = scale[row];
        if constexpr (CPT == 2) {
            h2 o;
            o[0] = (_Float16)(acc[r][0] * s);
            o[1] = (_Float16)(acc[r][1] * s);
            *(h2*)&Y[(size_t)row * OC + tx * 2] = o;
        } else {
            Y[(size_t)row * OC + tx] = (_Float16)(acc[r][0] * s);
        }
    }
}

// ---------------------------------------------------------------------------
// pull aggregation + fused epilogue over fp16 rows:
//   out[node,:] = norm_dst[node] * sum_j T[edge_src[j],:] + bias  (opt. relu)
// FEAT/8 lanes per node (16 B fp16 loads), fp32 accumulate, 4x edge unroll.
// OUT_HALF: write fp16 (hidden layer) vs fp32 (final output).
// ---------------------------------------------------------------------------
template <int FEAT, bool RELU, bool OUT_HALF>
__global__ __launch_bounds__(256) void gather_agg_kernel(
    const _Float16* __restrict__ T, const int* __restrict__ row_ptr,
    const int* __restrict__ edge_src, const float* __restrict__ norm_dst,
    const float* __restrict__ bias, void* __restrict__ outv, int n) {
    constexpr int TPN = FEAT / 8;    // lanes per node (16 / 8)
    constexpr int NPB = 256 / TPN;   // nodes per block (16 / 32)
    const int node = blockIdx.x * NPB + threadIdx.x / TPN;
    const int f8 = threadIdx.x % TPN;
    if (node >= n) return;
    const int beg = row_ptr[node];
    const int end = row_ptr[node + 1];
    const h8* T8 = (const h8*)T;  // row stride = TPN vectors

    f8v acc = (f8v)0.0f;
    int j = beg;
    for (; j + 3 < end; j += 4) {
        const int s0 = edge_src[j + 0];
        const int s1 = edge_src[j + 1];
        const int s2 = edge_src[j + 2];
        const int s3 = edge_src[j + 3];
        const h8 a0 = T8[(size_t)s0 * TPN + f8];
        const h8 a1 = T8[(size_t)s1 * TPN + f8];
        const h8 a2 = T8[(size_t)s2 * TPN + f8];
        const h8 a3 = T8[(size_t)s3 * TPN + f8];
        acc += __builtin_convertvector(a0, f8v);
        acc += __builtin_convertvector(a1, f8v);
        acc += __builtin_convertvector(a2, f8v);
        acc += __builtin_convertvector(a3, f8v);
    }
    for (; j < end; ++j) {
        const int s = edge_src[j];
        acc += __builtin_convertvector(T8[(size_t)s * TPN + f8], f8v);
    }

    const float nd = norm_dst[node];
    float r[8];
#pragma unroll
    for (int k = 0; k < 8; ++k) {
        r[k] = acc[k] * nd + bias[f8 * 8 + k];
        if constexpr (RELU) r[k] = fmaxf(r[k], 0.0f);
    }

    if constexpr (OUT_HALF) {
        _Float16* out = (_Float16*)outv;
        h8 o;
#pragma unroll
        for (int k = 0; k < 8; ++k) o[k] = (_Float16)r[k];
        *(h8*)&out[(size_t)node * FEAT + f8 * 8] = o;
    } else {
        float* out = (float*)outv;
        float4 o0 = make_float4(r[0], r[1], r[2], r[3]);
        float4 o1 = make_float4(r[4], r[5], r[6], r[7]);
        *(float4*)&out[(size_t)node * FEAT + f8 * 8] = o0;
        *(float4*)&out[(size_t)node * FEAT + f8 * 8 + 4] = o1;
    }
}

extern "C" void kernel_launch(void* const* d_in, const int* in_sizes, int n_in,
                              void* d_out, int out_size, void* d_ws, size_t ws_size,
                              hipStream_t stream) {
    const float* x   = (const float*)d_in[0];   // [N,128]
    const int*   src = (const int*)d_in[1];     // [E]
    const int*   dst = (const int*)d_in[2];     // [E]
    const float* W1  = (const float*)d_in[3];   // [128,128]
    const float* b1  = (const float*)d_in[4];   // [128]
    const float* W2  = (const float*)d_in[5];   // [128,64]
    const float* b2  = (const float*)d_in[6];   // [64]
    float* out = (float*)d_out;

    const int N = in_sizes[0] / N_FEATS_IN;     // 100000
    const int E = in_sizes[1];                  // 1600000
    const int B = (N + 1023) / 1024;            // scan blocks (98 <= 256)

    // workspace layout, 4-byte words, 16B-aligned regions
    auto align4 = [](size_t w) { return (w + 3) & ~(size_t)3; };
    char* base = (char*)d_ws;
    size_t off = 0;
    auto take = [&](size_t words) {
        char* p = base + off * 4;
        off = align4(off + words);
        return p;
    };
    int*   deg_out  = (int*)take(N);            // contiguous w/ deg_in, cursor
    int*   deg_in   = (int*)take(N);
    int*   cursor   = (int*)take(N);
    int*   row_ptr  = (int*)take(N + 1);
    int*   bsum     = (int*)take(256);
    int*   boff     = (int*)take(256);
    int*   edge_src = (int*)take(E);
    float* norms    = (float*)take(2 * (size_t)N);
    _Float16* t1    = (_Float16*)take((size_t)N * 64);  // N x 128 fp16
    _Float16* h1    = (_Float16*)take((size_t)N * 64);  // N x 128 fp16
    _Float16* t2    = (_Float16*)take((size_t)N * 32);  // N x 64  fp16
    float* norm_src = norms;
    float* norm_dst = norms + N;

    // zero deg_out, deg_in, cursor (contiguous 3N ints)
    hipMemsetAsync(deg_out, 0, (size_t)3 * N * sizeof(int), stream);

    // ---- CSR build ----
    degree_kernel<<<(E + 255) / 256, 256, 0, stream>>>(src, dst, deg_out, deg_in, E);
    norm_kernel<<<(2 * N + 255) / 256, 256, 0, stream>>>(deg_out, norms, 2 * N);
    scan1_kernel<<<B, 256, 0, stream>>>(deg_in, row_ptr, bsum, N);
    scan2_kernel<<<1, 256, 0, stream>>>(bsum, boff, row_ptr, B, N);
    scan3_kernel<<<B, 256, 0, stream>>>(row_ptr, boff, N);
    bucket_kernel<<<(E + 255) / 256, 256, 0, stream>>>(src, dst, row_ptr, cursor,
                                                       edge_src, E);

    // ---- layer 1 ----
    gemm_scale_kernel<128, false><<<(N + 31) / 32, 256, 0, stream>>>(
        x, W1, norm_src, t1, N);
    gather_agg_kernel<128, true, true><<<(N + 15) / 16, 256, 0, stream>>>(
        t1, row_ptr, edge_src, norm_dst, b1, h1, N);

    // ---- layer 2 ----
    gemm_scale_kernel<64, true><<<(N + 31) / 32, 256, 0, stream>>>(
        h1, W2, norm_src, t2, N);
    gather_agg_kernel<64, false, false><<<(N + 31) / 32, 256, 0, stream>>>(
        t2, row_ptr, edge_src, norm_dst, b2, out, N);
}

// Round 4
// 534.705 us; speedup vs baseline: 8.3937x; 1.1186x over previous
//
#include <hip/hip_runtime.h>
#include <hip/hip_bf16.h>

#define N_FEATS_IN 128
#define CSTRIDE 16  // counter padding: one counter per 64B line

typedef _Float16 h8 __attribute__((ext_vector_type(8)));
typedef _Float16 h2 __attribute__((ext_vector_type(2)));
typedef float    f8v __attribute__((ext_vector_type(8)));

// ---------------------------------------------------------------------------
// fused rank + degree: pos[e] = cnt_in[dst[e]]++ (rank), cnt_out[src[e]]++
// counters padded to 1 per 64B line to kill hot-line serialization.
// ---------------------------------------------------------------------------
__global__ __launch_bounds__(256) void rank_degree_kernel(
    const int* __restrict__ src, const int* __restrict__ dst,
    int* __restrict__ cnt_out, int* __restrict__ cnt_in,
    int* __restrict__ pos, int nE) {
    int e = blockIdx.x * blockDim.x + threadIdx.x;
    if (e >= nE) return;
    const int s = src[e];
    const int d = dst[e];
    pos[e] = atomicAdd(&cnt_in[(size_t)d * CSTRIDE], 1);
    atomicAdd(&cnt_out[(size_t)s * CSTRIDE], 1);
}

// norm[i] = rsqrt(max(deg,1));  i<N -> cnt_out[i], else cnt_in[i-N] (strided)
__global__ __launch_bounds__(256) void norm_kernel(
    const int* __restrict__ cnt_out, const int* __restrict__ cnt_in,
    float* __restrict__ norm, int N) {
    int i = blockIdx.x * blockDim.x + threadIdx.x;
    if (i >= 2 * N) return;
    const int v = (i < N) ? cnt_out[(size_t)i * CSTRIDE]
                          : cnt_in[(size_t)(i - N) * CSTRIDE];
    norm[i] = rsqrtf(fmaxf((float)v, 1.0f));
}

// ---------------------------------------------------------------------------
// 3-kernel exclusive scan of cnt_in (strided) -> row_ptr[0..n], row_ptr[n]=E
// ---------------------------------------------------------------------------
__global__ __launch_bounds__(256) void scan1_kernel(
    const int* __restrict__ cnt, int* __restrict__ rp,
    int* __restrict__ bsum, int n) {
    __shared__ int ws[4];
    const int t = threadIdx.x;
    const int i0 = blockIdx.x * 1024 + t * 4;
    const int v0 = (i0 + 0 < n) ? cnt[(size_t)(i0 + 0) * CSTRIDE] : 0;
    const int v1 = (i0 + 1 < n) ? cnt[(size_t)(i0 + 1) * CSTRIDE] : 0;
    const int v2 = (i0 + 2 < n) ? cnt[(size_t)(i0 + 2) * CSTRIDE] : 0;
    const int v3 = (i0 + 3 < n) ? cnt[(size_t)(i0 + 3) * CSTRIDE] : 0;
    const int tsum = v0 + v1 + v2 + v3;
    const int lane = t & 63, wid = t >> 6;
    int inc = tsum;
    for (int off = 1; off < 64; off <<= 1) {
        int u = __shfl_up(inc, off, 64);
        if (lane >= off) inc += u;
    }
    if (lane == 63) ws[wid] = inc;
    __syncthreads();
    int woff = 0;
#pragma unroll
    for (int w = 0; w < 4; ++w) woff += (w < wid) ? ws[w] : 0;
    const int excl = woff + inc - tsum;
    if (i0 + 0 < n) rp[i0 + 0] = excl;
    if (i0 + 1 < n) rp[i0 + 1] = excl + v0;
    if (i0 + 2 < n) rp[i0 + 2] = excl + v0 + v1;
    if (i0 + 3 < n) rp[i0 + 3] = excl + v0 + v1 + v2;
    if (t == 255) bsum[blockIdx.x] = woff + inc;
}

__global__ __launch_bounds__(256) void scan2_kernel(
    const int* __restrict__ bsum, int* __restrict__ boff,
    int* __restrict__ rp, int B, int n) {
    __shared__ int ws[4];
    const int t = threadIdx.x;
    const int v = (t < B) ? bsum[t] : 0;
    const int lane = t & 63, wid = t >> 6;
    int inc = v;
    for (int off = 1; off < 64; off <<= 1) {
        int u = __shfl_up(inc, off, 64);
        if (lane >= off) inc += u;
    }
    if (lane == 63) ws[wid] = inc;
    __syncthreads();
    int woff = 0;
#pragma unroll
    for (int w = 0; w < 4; ++w) woff += (w < wid) ? ws[w] : 0;
    if (t < B) boff[t] = woff + inc - v;
    if (t == 255) rp[n] = woff + inc;  // grand total = E
}

__global__ __launch_bounds__(256) void scan3_kernel(
    int* __restrict__ rp, const int* __restrict__ boff, int n) {
    const int add = boff[blockIdx.x];
    const int i0 = blockIdx.x * 1024 + threadIdx.x * 4;
    if (i0 + 3 < n) {
        int4 v = *(int4*)&rp[i0];
        v.x += add; v.y += add; v.z += add; v.w += add;
        *(int4*)&rp[i0] = v;
    } else {
#pragma unroll
        for (int k = 0; k < 4; ++k)
            if (i0 + k < n) rp[i0 + k] += add;
    }
}

// ---------------------------------------------------------------------------
// atomic-free bucket fill: edge_src[row_ptr[dst[e]] + pos[e]] = src[e]
// pos[e] is the unique per-dst rank from rank_degree_kernel.
// ---------------------------------------------------------------------------
__global__ __launch_bounds__(256) void bucket_kernel(
    const int* __restrict__ src, const int* __restrict__ dst,
    const int* __restrict__ row_ptr, const int* __restrict__ pos,
    int* __restrict__ edge_src, int nE) {
    int e = blockIdx.x * blockDim.x + threadIdx.x;
    if (e >= nE) return;
    edge_src[row_ptr[dst[e]] + pos[e]] = src[e];
}

// ---------------------------------------------------------------------------
// Y[n,OC] = (X[n,128] @ W[128,OC]) * scale[n],  Y stored as fp16.
// X is fp32 (XHALF=false) or fp16 (XHALF=true); compute fp32.
// ---------------------------------------------------------------------------
template <int OC, bool XHALF>
__global__ __launch_bounds__(256) void gemm_scale_kernel(
    const void* __restrict__ Xv, const float* __restrict__ W,
    const float* __restrict__ scale, _Float16* __restrict__ Y, int n) {
    constexpr int K = 128;
    constexpr int ROWS = 32;
    constexpr int CPT = OC / 64;  // cols per thread

    __shared__ float Wl[K * OC];
    __shared__ float Xs[ROWS][K];

    const int tid = threadIdx.x;
    for (int i = tid; i < K * OC / 4; i += 256)
        ((float4*)Wl)[i] = ((const float4*)W)[i];

    const int row0 = blockIdx.x * ROWS;
    if constexpr (XHALF) {
        const _Float16* X = (const _Float16*)Xv;
        for (int i = tid; i < ROWS * K / 8; i += 256) {
            h8 v = ((const h8*)&X[(size_t)row0 * K])[i];
            f8v f = __builtin_convertvector(v, f8v);
#pragma unroll
            for (int k = 0; k < 8; ++k) (&Xs[0][0])[i * 8 + k] = f[k];
        }
    } else {
        const float* X = (const float*)Xv;
        for (int i = tid; i < ROWS * K / 4; i += 256)
            ((float4*)&Xs[0][0])[i] = ((const float4*)&X[(size_t)row0 * K])[i];
    }
    __syncthreads();

    const int tx = tid & 63;
    const int ty = tid >> 6;

    float acc[8][CPT];
#pragma unroll
    for (int r = 0; r < 8; ++r)
#pragma unroll
        for (int c = 0; c < CPT; ++c) acc[r][c] = 0.0f;

#pragma unroll 4
    for (int k4 = 0; k4 < K / 4; ++k4) {
        float4 xr[8];
#pragma unroll
        for (int r = 0; r < 8; ++r)
            xr[r] = *(const float4*)&Xs[ty * 8 + r][k4 * 4];
#pragma unroll
        for (int j = 0; j < 4; ++j) {
            const int k = k4 * 4 + j;
            float w[CPT];
            if constexpr (CPT == 2) {
                float2 wv = *(const float2*)&Wl[k * OC + tx * 2];
                w[0] = wv.x; w[1] = wv.y;
            } else {
                w[0] = Wl[k * OC + tx];
            }
#pragma unroll
            for (int r = 0; r < 8; ++r) {
                const float xv = (j == 0) ? xr[r].x : (j == 1) ? xr[r].y
                               : (j == 2) ? xr[r].z : xr[r].w;
#pragma unroll
                for (int c = 0; c < CPT; ++c) acc[r][c] += xv * w[c];
            }
        }
    }

#pragma unroll
    for (int r = 0; r < 8; ++r) {
        const int row = row0 + ty * 8 + r;
        if (row >= n) continue;
        const float s = scale[row];
        if constexpr (CPT == 2) {
            h2 o;
            o[0] = (_Float16)(acc[r][0] * s);
            o[1] = (_Float16)(acc[r][1] * s);
            *(h2*)&Y[(size_t)row * OC + tx * 2] = o;
        } else {
            Y[(size_t)row * OC + tx] = (_Float16)(acc[r][0] * s);
        }
    }
}

// ---------------------------------------------------------------------------
// pull aggregation + fused epilogue over fp16 rows:
//   out[node,:] = norm_dst[node] * sum_j T[edge_src[j],:] + bias  (opt. relu)
// ---------------------------------------------------------------------------
template <int FEAT, bool RELU, bool OUT_HALF>
__global__ __launch_bounds__(256) void gather_agg_kernel(
    const _Float16* __restrict__ T, const int* __restrict__ row_ptr,
    const int* __restrict__ edge_src, const float* __restrict__ norm_dst,
    const float* __restrict__ bias, void* __restrict__ outv, int n) {
    constexpr int TPN = FEAT / 8;    // lanes per node (16 / 8)
    constexpr int NPB = 256 / TPN;   // nodes per block (16 / 32)
    const int node = blockIdx.x * NPB + threadIdx.x / TPN;
    const int f8 = threadIdx.x % TPN;
    if (node >= n) return;
    const int beg = row_ptr[node];
    const int end = row_ptr[node + 1];
    const h8* T8 = (const h8*)T;  // row stride = TPN vectors

    f8v acc = (f8v)0.0f;
    int j = beg;
    for (; j + 3 < end; j += 4) {
        const int s0 = edge_src[j + 0];
        const int s1 = edge_src[j + 1];
        const int s2 = edge_src[j + 2];
        const int s3 = edge_src[j + 3];
        const h8 a0 = T8[(size_t)s0 * TPN + f8];
        const h8 a1 = T8[(size_t)s1 * TPN + f8];
        const h8 a2 = T8[(size_t)s2 * TPN + f8];
        const h8 a3 = T8[(size_t)s3 * TPN + f8];
        acc += __builtin_convertvector(a0, f8v);
        acc += __builtin_convertvector(a1, f8v);
        acc += __builtin_convertvector(a2, f8v);
        acc += __builtin_convertvector(a3, f8v);
    }
    for (; j < end; ++j) {
        const int s = edge_src[j];
        acc += __builtin_convertvector(T8[(size_t)s * TPN + f8], f8v);
    }

    const float nd = norm_dst[node];
    float r[8];
#pragma unroll
    for (int k = 0; k < 8; ++k) {
        r[k] = acc[k] * nd + bias[f8 * 8 + k];
        if constexpr (RELU) r[k] = fmaxf(r[k], 0.0f);
    }

    if constexpr (OUT_HALF) {
        _Float16* out = (_Float16*)outv;
        h8 o;
#pragma unroll
        for (int k = 0; k < 8; ++k) o[k] = (_Float16)r[k];
        *(h8*)&out[(size_t)node * FEAT + f8 * 8] = o;
    } else {
        float* out = (float*)outv;
        float4 o0 = make_float4(r[0], r[1], r[2], r[3]);
        float4 o1 = make_float4(r[4], r[5], r[6], r[7]);
        *(float4*)&out[(size_t)node * FEAT + f8 * 8] = o0;
        *(float4*)&out[(size_t)node * FEAT + f8 * 8 + 4] = o1;
    }
}

extern "C" void kernel_launch(void* const* d_in, const int* in_sizes, int n_in,
                              void* d_out, int out_size, void* d_ws, size_t ws_size,
                              hipStream_t stream) {
    const float* x   = (const float*)d_in[0];   // [N,128]
    const int*   src = (const int*)d_in[1];     // [E]
    const int*   dst = (const int*)d_in[2];     // [E]
    const float* W1  = (const float*)d_in[3];   // [128,128]
    const float* b1  = (const float*)d_in[4];   // [128]
    const float* W2  = (const float*)d_in[5];   // [128,64]
    const float* b2  = (const float*)d_in[6];   // [64]
    float* out = (float*)d_out;

    const int N = in_sizes[0] / N_FEATS_IN;     // 100000
    const int E = in_sizes[1];                  // 1600000
    const int B = (N + 1023) / 1024;            // scan blocks (98 <= 256)

    // workspace layout, 4-byte words, 16B-aligned regions
    auto align4 = [](size_t w) { return (w + 3) & ~(size_t)3; };
    char* base = (char*)d_ws;
    size_t off = 0;
    auto take = [&](size_t words) {
        char* p = base + off * 4;
        off = align4(off + words);
        return p;
    };
    int*   cnt_out  = (int*)take((size_t)N * CSTRIDE);  // padded counters
    int*   cnt_in   = (int*)take((size_t)N * CSTRIDE);  // (contiguous w/ cnt_out)
    int*   pos      = (int*)take(E);
    int*   row_ptr  = (int*)take(N + 1);
    int*   bsum     = (int*)take(256);
    int*   boff     = (int*)take(256);
    int*   edge_src = (int*)take(E);
    float* norms    = (float*)take(2 * (size_t)N);
    _Float16* t1    = (_Float16*)take((size_t)N * 64);  // N x 128 fp16
    _Float16* h1    = (_Float16*)take((size_t)N * 64);  // N x 128 fp16
    _Float16* t2    = (_Float16*)take((size_t)N * 32);  // N x 64  fp16
    float* norm_src = norms;
    float* norm_dst = norms + N;

    // zero both padded counter arrays (contiguous, 2*N*CSTRIDE ints)
    hipMemsetAsync(cnt_out, 0, (size_t)2 * N * CSTRIDE * sizeof(int), stream);

    // ---- CSR build ----
    rank_degree_kernel<<<(E + 255) / 256, 256, 0, stream>>>(
        src, dst, cnt_out, cnt_in, pos, E);
    norm_kernel<<<(2 * N + 255) / 256, 256, 0, stream>>>(cnt_out, cnt_in, norms, N);
    scan1_kernel<<<B, 256, 0, stream>>>(cnt_in, row_ptr, bsum, N);
    scan2_kernel<<<1, 256, 0, stream>>>(bsum, boff, row_ptr, B, N);
    scan3_kernel<<<B, 256, 0, stream>>>(row_ptr, boff, N);
    bucket_kernel<<<(E + 255) / 256, 256, 0, stream>>>(
        src, dst, row_ptr, pos, edge_src, E);

    // ---- layer 1 ----
    gemm_scale_kernel<128, false><<<(N + 31) / 32, 256, 0, stream>>>(
        x, W1, norm_src, t1, N);
    gather_agg_kernel<128, true, true><<<(N + 15) / 16, 256, 0, stream>>>(
        t1, row_ptr, edge_src, norm_dst, b1, h1, N);

    // ---- layer 2 ----
    gemm_scale_kernel<64, true><<<(N + 31) / 32, 256, 0, stream>>>(
        h1, W2, norm_src, t2, N);
    gather_agg_kernel<64, false, false><<<(N + 31) / 32, 256, 0, stream>>>(
        t2, row_ptr, edge_src, norm_dst, b2, out, N);
}

// Round 5
// 473.081 us; speedup vs baseline: 9.4871x; 1.1303x over previous
//
#include <hip/hip_runtime.h>
#include <hip/hip_bf16.h>

#define N_FEATS_IN 128
#define BK_BITS 8
#define BK_SIZE 256      // nodes per bucket
#define EPB 4096         // edges per histogram/scatter block
#define MAXNB 512        // max buckets (N <= 131072)

typedef _Float16 h8 __attribute__((ext_vector_type(8)));
typedef _Float16 h2 __attribute__((ext_vector_type(2)));
typedef float    f8v __attribute__((ext_vector_type(8)));

// ---------------------------------------------------------------------------
// scan helpers
// ---------------------------------------------------------------------------
__device__ inline int wave_incl_scan(int v) {
    const int lane = threadIdx.x & 63;
    for (int off = 1; off < 64; off <<= 1) {
        int u = __shfl_up(v, off, 64);
        if (lane >= off) v += u;
    }
    return v;
}

// 256-thread block: exclusive prefix of s; ws = LDS int[4]. Caller syncs before
// reusing ws. If total != nullptr, receives block-wide sum.
__device__ inline int block_excl_scan(int s, int* ws, int* total) {
    const int lane = threadIdx.x & 63, wid = threadIdx.x >> 6;
    int inc = wave_incl_scan(s);
    if (lane == 63) ws[wid] = inc;
    __syncthreads();
    int woff = 0;
#pragma unroll
    for (int w = 0; w < 4; ++w) woff += (w < wid) ? ws[w] : 0;
    if (total) *total = ws[0] + ws[1] + ws[2] + ws[3];
    return woff + inc - s;
}

// ---------------------------------------------------------------------------
// K1: per-block bucket histogram of dst (LDS) -> blk_hist[blk][NB];
//     fused deg_out histogram of src via packed-u16 global atomics
//     (2 counters per word, 32 per line: max same-line density).
// ---------------------------------------------------------------------------
__global__ __launch_bounds__(256) void hist_kernel(
    const int* __restrict__ src, const int* __restrict__ dst,
    int* __restrict__ blk_hist, unsigned int* __restrict__ deg_out_pk,
    int E, int NB) {
    __shared__ int h[MAXNB];
    const int t = threadIdx.x;
    for (int i = t; i < NB; i += 256) h[i] = 0;
    __syncthreads();
    const int base = blockIdx.x * EPB;
    const int end = min(base + EPB, E);
    for (int e = base + t; e < end; e += 256) {
        const int d = dst[e];
        atomicAdd(&h[d >> BK_BITS], 1);
        const int s = src[e];
        atomicAdd(&deg_out_pk[s >> 1], (s & 1) ? (1u << 16) : 1u);
    }
    __syncthreads();
    for (int i = t; i < NB; i += 256)
        blk_hist[(size_t)blockIdx.x * NB + i] = h[i];
}

// K2a: tot[b] = sum over blocks of blk_hist[blk][b]   (one block per bucket)
__global__ __launch_bounds__(256) void colsum_kernel(
    const int* __restrict__ blk_hist, int* __restrict__ tot, int NBLK, int NB) {
    __shared__ int ws[4];
    const int b = blockIdx.x;
    int s = 0;
    for (int r = threadIdx.x; r < NBLK; r += 256)
        s += blk_hist[(size_t)r * NB + b];
    int tt;
    block_excl_scan(s, ws, &tt);
    if (threadIdx.x == 0) tot[b] = tt;
}

// K2b: single block: gb_off = exclusive scan of tot[0..NB); gb_off[NB]=E,
//      row_ptr[N]=E.
__global__ __launch_bounds__(256) void bscan_kernel(
    const int* __restrict__ tot, int* __restrict__ gb_off,
    int* __restrict__ row_ptr, int NB, int N, int E) {
    __shared__ int ws[4];
    const int t = threadIdx.x;
    const int a = (2 * t < NB) ? tot[2 * t] : 0;
    const int b = (2 * t + 1 < NB) ? tot[2 * t + 1] : 0;
    const int excl = block_excl_scan(a + b, ws, nullptr);
    if (2 * t < NB) gb_off[2 * t] = excl;
    if (2 * t + 1 < NB) gb_off[2 * t + 1] = excl + a;
    if (t == 0) { gb_off[NB] = E; row_ptr[N] = E; }
}

// K2c: per column b: blk_hist[blk][b] <- gb_off[b] + prefix over blk
__global__ __launch_bounds__(256) void colscan_kernel(
    int* __restrict__ blk_hist, const int* __restrict__ gb_off,
    int NBLK, int NB) {
    __shared__ int ws[4];
    const int b = blockIdx.x;
    const int t = threadIdx.x;
    const int r0 = 2 * t, r1 = 2 * t + 1;
    const int a = (r0 < NBLK) ? blk_hist[(size_t)r0 * NB + b] : 0;
    const int c = (r1 < NBLK) ? blk_hist[(size_t)r1 * NB + b] : 0;
    const int excl = block_excl_scan(a + c, ws, nullptr);
    const int base = gb_off[b];
    if (r0 < NBLK) blk_hist[(size_t)r0 * NB + b] = base + excl;
    if (r1 < NBLK) blk_hist[(size_t)r1 * NB + b] = base + excl + a;
}

// K3: scatter edges into bucket-grouped ebuf using LDS cursors (no global
//     atomics; cursor base = this block's absolute offsets from K2c).
__global__ __launch_bounds__(256) void scatter_kernel(
    const int* __restrict__ src, const int* __restrict__ dst,
    const int* __restrict__ blk_hist, uint2* __restrict__ ebuf,
    int E, int NB) {
    __shared__ int cur[MAXNB];
    const int t = threadIdx.x;
    for (int i = t; i < NB; i += 256)
        cur[i] = blk_hist[(size_t)blockIdx.x * NB + i];
    __syncthreads();
    const int base = blockIdx.x * EPB;
    const int end = min(base + EPB, E);
    for (int e = base + t; e < end; e += 256) {
        const int d = dst[e];
        const int p = atomicAdd(&cur[d >> BK_BITS], 1);
        ebuf[p] = make_uint2((unsigned)src[e], (unsigned)d);
    }
}

// K4: per-bucket exact CSR: row_ptr, norm_dst (fused), edge_src.
__global__ __launch_bounds__(256) void bucket_csr_kernel(
    const uint2* __restrict__ ebuf, const int* __restrict__ gb_off,
    int* __restrict__ row_ptr, float* __restrict__ norm_dst,
    int* __restrict__ edge_src, int N) {
    __shared__ int cnt[BK_SIZE];
    __shared__ int lro[BK_SIZE];
    __shared__ int ws[4];
    const int b = blockIdx.x;
    const int t = threadIdx.x;
    const int beg = gb_off[b], end = gb_off[b + 1];

    cnt[t] = 0;
    __syncthreads();
    for (int j = beg + t; j < end; j += 256)
        atomicAdd(&cnt[ebuf[j].y & (BK_SIZE - 1)], 1);
    __syncthreads();

    const int v = cnt[t];
    const int excl = block_excl_scan(v, ws, nullptr);
    lro[t] = beg + excl;
    const int node = b * BK_SIZE + t;
    if (node < N) {
        row_ptr[node] = beg + excl;
        norm_dst[node] = rsqrtf(fmaxf((float)v, 1.0f));
    }
    cnt[t] = 0;  // reuse as cursor
    __syncthreads();

    for (int j = beg + t; j < end; j += 256) {
        const uint2 ed = ebuf[j];
        const int dl = ed.y & (BK_SIZE - 1);
        const int p = atomicAdd(&cnt[dl], 1);
        edge_src[lro[dl] + p] = (int)ed.x;
    }
}

// norm_src[i] = rsqrt(max(deg_out,1)) from packed-u16 counters
__global__ __launch_bounds__(256) void norm_src_kernel(
    const unsigned int* __restrict__ pk, float* __restrict__ norm, int N) {
    const int i = blockIdx.x * blockDim.x + threadIdx.x;
    if (i >= N) return;
    unsigned int v = pk[i >> 1];
    v = (i & 1) ? (v >> 16) : (v & 0xffffu);
    norm[i] = rsqrtf(fmaxf((float)v, 1.0f));
}

// ---------------------------------------------------------------------------
// Y[n,OC] = (X[n,128] @ W[128,OC]) * scale[n],  Y stored as fp16.
// ---------------------------------------------------------------------------
template <int OC, bool XHALF>
__global__ __launch_bounds__(256) void gemm_scale_kernel(
    const void* __restrict__ Xv, const float* __restrict__ W,
    const float* __restrict__ scale, _Float16* __restrict__ Y, int n) {
    constexpr int K = 128;
    constexpr int ROWS = 32;
    constexpr int CPT = OC / 64;

    __shared__ float Wl[K * OC];
    __shared__ float Xs[ROWS][K];

    const int tid = threadIdx.x;
    for (int i = tid; i < K * OC / 4; i += 256)
        ((float4*)Wl)[i] = ((const float4*)W)[i];

    const int row0 = blockIdx.x * ROWS;
    if constexpr (XHALF) {
        const _Float16* X = (const _Float16*)Xv;
        for (int i = tid; i < ROWS * K / 8; i += 256) {
            h8 v = ((const h8*)&X[(size_t)row0 * K])[i];
            f8v f = __builtin_convertvector(v, f8v);
#pragma unroll
            for (int k = 0; k < 8; ++k) (&Xs[0][0])[i * 8 + k] = f[k];
        }
    } else {
        const float* X = (const float*)Xv;
        for (int i = tid; i < ROWS * K / 4; i += 256)
            ((float4*)&Xs[0][0])[i] = ((const float4*)&X[(size_t)row0 * K])[i];
    }
    __syncthreads();

    const int tx = tid & 63;
    const int ty = tid >> 6;

    float acc[8][CPT];
#pragma unroll
    for (int r = 0; r < 8; ++r)
#pragma unroll
        for (int c = 0; c < CPT; ++c) acc[r][c] = 0.0f;

#pragma unroll 4
    for (int k4 = 0; k4 < K / 4; ++k4) {
        float4 xr[8];
#pragma unroll
        for (int r = 0; r < 8; ++r)
            xr[r] = *(const float4*)&Xs[ty * 8 + r][k4 * 4];
#pragma unroll
        for (int j = 0; j < 4; ++j) {
            const int k = k4 * 4 + j;
            float w[CPT];
            if constexpr (CPT == 2) {
                float2 wv = *(const float2*)&Wl[k * OC + tx * 2];
                w[0] = wv.x; w[1] = wv.y;
            } else {
                w[0] = Wl[k * OC + tx];
            }
#pragma unroll
            for (int r = 0; r < 8; ++r) {
                const float xv = (j == 0) ? xr[r].x : (j == 1) ? xr[r].y
                               : (j == 2) ? xr[r].z : xr[r].w;
#pragma unroll
                for (int c = 0; c < CPT; ++c) acc[r][c] += xv * w[c];
            }
        }
    }

#pragma unroll
    for (int r = 0; r < 8; ++r) {
        const int row = row0 + ty * 8 + r;
        if (row >= n) continue;
        const float s = scale[row];
        if constexpr (CPT == 2) {
            h2 o;
            o[0] = (_Float16)(acc[r][0] * s);
            o[1] = (_Float16)(acc[r][1] * s);
            *(h2*)&Y[(size_t)row * OC + tx * 2] = o;
        } else {
            Y[(size_t)row * OC + tx] = (_Float16)(acc[r][0] * s);
        }
    }
}

// ---------------------------------------------------------------------------
// pull aggregation + fused epilogue over fp16 rows
// ---------------------------------------------------------------------------
template <int FEAT, bool RELU, bool OUT_HALF>
__global__ __launch_bounds__(256) void gather_agg_kernel(
    const _Float16* __restrict__ T, const int* __restrict__ row_ptr,
    const int* __restrict__ edge_src, const float* __restrict__ norm_dst,
    const float* __restrict__ bias, void* __restrict__ outv, int n) {
    constexpr int TPN = FEAT / 8;
    constexpr int NPB = 256 / TPN;
    const int node = blockIdx.x * NPB + threadIdx.x / TPN;
    const int f8 = threadIdx.x % TPN;
    if (node >= n) return;
    const int beg = row_ptr[node];
    const int end = row_ptr[node + 1];
    const h8* T8 = (const h8*)T;

    f8v acc = (f8v)0.0f;
    int j = beg;
    for (; j + 3 < end; j += 4) {
        const int s0 = edge_src[j + 0];
        const int s1 = edge_src[j + 1];
        const int s2 = edge_src[j + 2];
        const int s3 = edge_src[j + 3];
        const h8 a0 = T8[(size_t)s0 * TPN + f8];
        const h8 a1 = T8[(size_t)s1 * TPN + f8];
        const h8 a2 = T8[(size_t)s2 * TPN + f8];
        const h8 a3 = T8[(size_t)s3 * TPN + f8];
        acc += __builtin_convertvector(a0, f8v);
        acc += __builtin_convertvector(a1, f8v);
        acc += __builtin_convertvector(a2, f8v);
        acc += __builtin_convertvector(a3, f8v);
    }
    for (; j < end; ++j) {
        const int s = edge_src[j];
        acc += __builtin_convertvector(T8[(size_t)s * TPN + f8], f8v);
    }

    const float nd = norm_dst[node];
    float r[8];
#pragma unroll
    for (int k = 0; k < 8; ++k) {
        r[k] = acc[k] * nd + bias[f8 * 8 + k];
        if constexpr (RELU) r[k] = fmaxf(r[k], 0.0f);
    }

    if constexpr (OUT_HALF) {
        _Float16* out = (_Float16*)outv;
        h8 o;
#pragma unroll
        for (int k = 0; k < 8; ++k) o[k] = (_Float16)r[k];
        *(h8*)&out[(size_t)node * FEAT + f8 * 8] = o;
    } else {
        float* out = (float*)outv;
        float4 o0 = make_float4(r[0], r[1], r[2], r[3]);
        float4 o1 = make_float4(r[4], r[5], r[6], r[7]);
        *(float4*)&out[(size_t)node * FEAT + f8 * 8] = o0;
        *(float4*)&out[(size_t)node * FEAT + f8 * 8 + 4] = o1;
    }
}

extern "C" void kernel_launch(void* const* d_in, const int* in_sizes, int n_in,
                              void* d_out, int out_size, void* d_ws, size_t ws_size,
                              hipStream_t stream) {
    const float* x   = (const float*)d_in[0];   // [N,128]
    const int*   src = (const int*)d_in[1];     // [E]
    const int*   dst = (const int*)d_in[2];     // [E]
    const float* W1  = (const float*)d_in[3];   // [128,128]
    const float* b1  = (const float*)d_in[4];   // [128]
    const float* W2  = (const float*)d_in[5];   // [128,64]
    const float* b2  = (const float*)d_in[6];   // [64]
    float* out = (float*)d_out;

    const int N = in_sizes[0] / N_FEATS_IN;     // 100000
    const int E = in_sizes[1];                  // 1600000
    const int NB = (N + BK_SIZE - 1) / BK_SIZE; // 391 buckets
    const int NBLK = (E + EPB - 1) / EPB;       // 391 edge blocks

    // workspace layout, 4-byte words, 16B-aligned regions
    auto align4 = [](size_t w) { return (w + 3) & ~(size_t)3; };
    char* base = (char*)d_ws;
    size_t off = 0;
    auto take = [&](size_t words) {
        char* p = base + off * 4;
        off = align4(off + words);
        return p;
    };
    unsigned int* deg_pk = (unsigned int*)take((size_t)(N + 1) / 2 + 1);
    int*   tot      = (int*)take(NB);
    int*   gb_off   = (int*)take(NB + 1);
    int*   blk_hist = (int*)take((size_t)NBLK * NB);
    uint2* ebuf     = (uint2*)take((size_t)2 * E);
    int*   row_ptr  = (int*)take(N + 1);
    int*   edge_src = (int*)take(E);
    float* norms    = (float*)take(2 * (size_t)N);
    _Float16* t1    = (_Float16*)take((size_t)N * 64);  // N x 128 fp16
    _Float16* h1    = (_Float16*)take((size_t)N * 64);  // N x 128 fp16
    _Float16* t2    = (_Float16*)take((size_t)N * 32);  // N x 64  fp16
    float* norm_src = norms;
    float* norm_dst = norms + N;

    // zero only the packed deg_out counters (~200 KB)
    hipMemsetAsync(deg_pk, 0, ((size_t)(N + 1) / 2 + 1) * sizeof(unsigned int),
                   stream);

    // ---- CSR build (counting sort by dst, LDS histograms) ----
    hist_kernel<<<NBLK, 256, 0, stream>>>(src, dst, blk_hist, deg_pk, E, NB);
    norm_src_kernel<<<(N + 255) / 256, 256, 0, stream>>>(deg_pk, norm_src, N);
    colsum_kernel<<<NB, 256, 0, stream>>>(blk_hist, tot, NBLK, NB);
    bscan_kernel<<<1, 256, 0, stream>>>(tot, gb_off, row_ptr, NB, N, E);
    colscan_kernel<<<NB, 256, 0, stream>>>(blk_hist, gb_off, NBLK, NB);
    scatter_kernel<<<NBLK, 256, 0, stream>>>(src, dst, blk_hist, ebuf, E, NB);
    bucket_csr_kernel<<<NB, 256, 0, stream>>>(ebuf, gb_off, row_ptr, norm_dst,
                                              edge_src, N);

    // ---- layer 1 ----
    gemm_scale_kernel<128, false><<<(N + 31) / 32, 256, 0, stream>>>(
        x, W1, norm_src, t1, N);
    gather_agg_kernel<128, true, true><<<(N + 15) / 16, 256, 0, stream>>>(
        t1, row_ptr, edge_src, norm_dst, b1, h1, N);

    // ---- layer 2 ----
    gemm_scale_kernel<64, true><<<(N + 31) / 32, 256, 0, stream>>>(
        h1, W2, norm_src, t2, N);
    gather_agg_kernel<64, false, false><<<(N + 31) / 32, 256, 0, stream>>>(
        t2, row_ptr, edge_src, norm_dst, b2, out, N);
}

// Round 6
// 389.267 us; speedup vs baseline: 11.5298x; 1.2153x over previous
//
#include <hip/hip_runtime.h>
#include <hip/hip_bf16.h>

#define N_FEATS_IN 128
#define BK_BITS 8
#define BK_SIZE 256      // nodes per bucket
#define EPB 4096         // edges per histogram/scatter block
#define MAXNB 512        // max buckets (N <= 131072)

typedef _Float16 h8 __attribute__((ext_vector_type(8)));
typedef float    f4v __attribute__((ext_vector_type(4)));
typedef float    f8v __attribute__((ext_vector_type(8)));

// ---------------------------------------------------------------------------
// scan helpers
// ---------------------------------------------------------------------------
__device__ inline int wave_incl_scan(int v) {
    const int lane = threadIdx.x & 63;
    for (int off = 1; off < 64; off <<= 1) {
        int u = __shfl_up(v, off, 64);
        if (lane >= off) v += u;
    }
    return v;
}

__device__ inline int block_excl_scan(int s, int* ws, int* total) {
    const int lane = threadIdx.x & 63, wid = threadIdx.x >> 6;
    int inc = wave_incl_scan(s);
    if (lane == 63) ws[wid] = inc;
    __syncthreads();
    int woff = 0;
#pragma unroll
    for (int w = 0; w < 4; ++w) woff += (w < wid) ? ws[w] : 0;
    if (total) *total = ws[0] + ws[1] + ws[2] + ws[3];
    return woff + inc - s;
}

// ---------------------------------------------------------------------------
// K1: per-block bucket histogram of dst (LDS) -> blk_hist[blk][NB];
//     fused deg_out histogram of src via packed-u16 global atomics.
// ---------------------------------------------------------------------------
__global__ __launch_bounds__(256) void hist_kernel(
    const int* __restrict__ src, const int* __restrict__ dst,
    int* __restrict__ blk_hist, unsigned int* __restrict__ deg_out_pk,
    int E, int NB) {
    __shared__ int h[MAXNB];
    const int t = threadIdx.x;
    for (int i = t; i < NB; i += 256) h[i] = 0;
    __syncthreads();
    const int base = blockIdx.x * EPB;
    const int end = min(base + EPB, E);
    for (int e = base + t; e < end; e += 256) {
        const int d = dst[e];
        atomicAdd(&h[d >> BK_BITS], 1);
        const int s = src[e];
        atomicAdd(&deg_out_pk[s >> 1], (s & 1) ? (1u << 16) : 1u);
    }
    __syncthreads();
    for (int i = t; i < NB; i += 256)
        blk_hist[(size_t)blockIdx.x * NB + i] = h[i];
}

// K2a: tot[b] = sum over blocks of blk_hist[blk][b]
__global__ __launch_bounds__(256) void colsum_kernel(
    const int* __restrict__ blk_hist, int* __restrict__ tot, int NBLK, int NB) {
    __shared__ int ws[4];
    const int b = blockIdx.x;
    int s = 0;
    for (int r = threadIdx.x; r < NBLK; r += 256)
        s += blk_hist[(size_t)r * NB + b];
    int tt;
    block_excl_scan(s, ws, &tt);
    if (threadIdx.x == 0) tot[b] = tt;
}

// K2b: gb_off = exclusive scan of tot[0..NB); gb_off[NB]=E, row_ptr[N]=E
__global__ __launch_bounds__(256) void bscan_kernel(
    const int* __restrict__ tot, int* __restrict__ gb_off,
    int* __restrict__ row_ptr, int NB, int N, int E) {
    __shared__ int ws[4];
    const int t = threadIdx.x;
    const int a = (2 * t < NB) ? tot[2 * t] : 0;
    const int b = (2 * t + 1 < NB) ? tot[2 * t + 1] : 0;
    const int excl = block_excl_scan(a + b, ws, nullptr);
    if (2 * t < NB) gb_off[2 * t] = excl;
    if (2 * t + 1 < NB) gb_off[2 * t + 1] = excl + a;
    if (t == 0) { gb_off[NB] = E; row_ptr[N] = E; }
}

// K2c: per column b: blk_hist[blk][b] <- gb_off[b] + prefix over blk
__global__ __launch_bounds__(256) void colscan_kernel(
    int* __restrict__ blk_hist, const int* __restrict__ gb_off,
    int NBLK, int NB) {
    __shared__ int ws[4];
    const int b = blockIdx.x;
    const int t = threadIdx.x;
    const int r0 = 2 * t, r1 = 2 * t + 1;
    const int a = (r0 < NBLK) ? blk_hist[(size_t)r0 * NB + b] : 0;
    const int c = (r1 < NBLK) ? blk_hist[(size_t)r1 * NB + b] : 0;
    const int excl = block_excl_scan(a + c, ws, nullptr);
    const int base = gb_off[b];
    if (r0 < NBLK) blk_hist[(size_t)r0 * NB + b] = base + excl;
    if (r1 < NBLK) blk_hist[(size_t)r1 * NB + b] = base + excl + a;
}

// K3: scatter edges into bucket-grouped ebuf using LDS cursors
__global__ __launch_bounds__(256) void scatter_kernel(
    const int* __restrict__ src, const int* __restrict__ dst,
    const int* __restrict__ blk_hist, uint2* __restrict__ ebuf,
    int E, int NB) {
    __shared__ int cur[MAXNB];
    const int t = threadIdx.x;
    for (int i = t; i < NB; i += 256)
        cur[i] = blk_hist[(size_t)blockIdx.x * NB + i];
    __syncthreads();
    const int base = blockIdx.x * EPB;
    const int end = min(base + EPB, E);
    for (int e = base + t; e < end; e += 256) {
        const int d = dst[e];
        const int p = atomicAdd(&cur[d >> BK_BITS], 1);
        ebuf[p] = make_uint2((unsigned)src[e], (unsigned)d);
    }
}

// K4: per-bucket exact CSR: row_ptr, norm_dst (fused), edge_src
__global__ __launch_bounds__(256) void bucket_csr_kernel(
    const uint2* __restrict__ ebuf, const int* __restrict__ gb_off,
    int* __restrict__ row_ptr, float* __restrict__ norm_dst,
    int* __restrict__ edge_src, int N) {
    __shared__ int cnt[BK_SIZE];
    __shared__ int lro[BK_SIZE];
    __shared__ int ws[4];
    const int b = blockIdx.x;
    const int t = threadIdx.x;
    const int beg = gb_off[b], end = gb_off[b + 1];

    cnt[t] = 0;
    __syncthreads();
    for (int j = beg + t; j < end; j += 256)
        atomicAdd(&cnt[ebuf[j].y & (BK_SIZE - 1)], 1);
    __syncthreads();

    const int v = cnt[t];
    const int excl = block_excl_scan(v, ws, nullptr);
    lro[t] = beg + excl;
    const int node = b * BK_SIZE + t;
    if (node < N) {
        row_ptr[node] = beg + excl;
        norm_dst[node] = rsqrtf(fmaxf((float)v, 1.0f));
    }
    cnt[t] = 0;  // reuse as cursor
    __syncthreads();

    for (int j = beg + t; j < end; j += 256) {
        const uint2 ed = ebuf[j];
        const int dl = ed.y & (BK_SIZE - 1);
        const int p = atomicAdd(&cnt[dl], 1);
        edge_src[lro[dl] + p] = (int)ed.x;
    }
}

// norm_src[i] = rsqrt(max(deg_out,1)) from packed-u16 counters
__global__ __launch_bounds__(256) void norm_src_kernel(
    const unsigned int* __restrict__ pk, float* __restrict__ norm, int N) {
    const int i = blockIdx.x * blockDim.x + threadIdx.x;
    if (i >= N) return;
    unsigned int v = pk[i >> 1];
    v = (i & 1) ? (v >> 16) : (v & 0xffffu);
    norm[i] = rsqrtf(fmaxf((float)v, 1.0f));
}

// ---------------------------------------------------------------------------
// MFMA GEMM: Y[n,OC] = (X[n,128] @ W[128,OC]) * scale[n], Y fp16.
// mfma_f32_16x16x32_f16, fp32 accumulate. W pre-swizzled fp16 in LDS in
// B-fragment order: Wf[((t*4+s)*64 + lane)*8 + j] = W[32s+8q+j][16t+nl],
// lane = 16q+nl -> each lane reads a contiguous h8 (conflict-free b128).
// A-frag from global: lane holds X[row0+(lane&15)][32s+8*(lane>>4)+j].
// D: row = (lane>>4)*4 + reg, col = lane&15 (verified C/D layout).
// Block: 256 thr = 4 waves x 16 rows, x2 row-iters = 128 rows/block.
// ---------------------------------------------------------------------------
template <int OC, bool XHALF>
__global__ __launch_bounds__(256) void mfma_gemm_kernel(
    const void* __restrict__ Xv, const float* __restrict__ W,
    const float* __restrict__ scale, _Float16* __restrict__ Y, int n) {
    constexpr int K = 128;
    constexpr int NT = OC / 16;     // col tiles: 8 (OC=128) or 4 (OC=64)
    constexpr int RPB = 128;        // rows per block
    __shared__ _Float16 Wf[NT * 4 * 64 * 8];

    const int tid = threadIdx.x;
    // stage + swizzle W (fp32 -> fp16, B-fragment order)
    for (int i = tid; i < K * OC; i += 256) {
        const int k = i / OC, c = i % OC;
        const int t = c >> 4, s = k >> 5, q = (k >> 3) & 3, j = k & 7;
        Wf[(((t * 4 + s) * 4 + q) * 16 + (c & 15)) * 8 + j] = (_Float16)W[i];
    }
    __syncthreads();

    const int lane = tid & 63;
    const int wv = tid >> 6;
    const int m = lane & 15, q = lane >> 4;

#pragma unroll
    for (int it = 0; it < RPB / 64; ++it) {
        const int rbase = blockIdx.x * RPB + it * 64 + wv * 16;
        const int lrow = min(rbase + m, n - 1);  // clamp OOB loads

        h8 a[4];
        if constexpr (XHALF) {
            const _Float16* X = (const _Float16*)Xv;
            const _Float16* p = &X[(size_t)lrow * K + q * 8];
#pragma unroll
            for (int s = 0; s < 4; ++s) a[s] = *(const h8*)(p + s * 32);
        } else {
            const float* X = (const float*)Xv;
            const float* p = &X[(size_t)lrow * K + q * 8];
#pragma unroll
            for (int s = 0; s < 4; ++s) {
                const float4 u0 = *(const float4*)(p + s * 32);
                const float4 u1 = *(const float4*)(p + s * 32 + 4);
                h8 v;
                v[0] = (_Float16)u0.x; v[1] = (_Float16)u0.y;
                v[2] = (_Float16)u0.z; v[3] = (_Float16)u0.w;
                v[4] = (_Float16)u1.x; v[5] = (_Float16)u1.y;
                v[6] = (_Float16)u1.z; v[7] = (_Float16)u1.w;
                a[s] = v;
            }
        }

        f4v acc[NT];
#pragma unroll
        for (int t = 0; t < NT; ++t) acc[t] = (f4v)0.0f;

#pragma unroll
        for (int s = 0; s < 4; ++s) {
#pragma unroll
            for (int t = 0; t < NT; ++t) {
                const h8 b = *(const h8*)&Wf[((t * 4 + s) * 64 + lane) * 8];
                acc[t] = __builtin_amdgcn_mfma_f32_16x16x32_f16(
                    a[s], b, acc[t], 0, 0, 0);
            }
        }

#pragma unroll
        for (int r = 0; r < 4; ++r) {
            const int orow = rbase + q * 4 + r;
            if (orow < n) {
                const float sc = scale[orow];
#pragma unroll
                for (int t = 0; t < NT; ++t)
                    Y[(size_t)orow * OC + t * 16 + m] =
                        (_Float16)(acc[t][r] * sc);
            }
        }
    }
}

// ---------------------------------------------------------------------------
// pull aggregation + fused epilogue over fp16 rows
// ---------------------------------------------------------------------------
template <int FEAT, bool RELU, bool OUT_HALF>
__global__ __launch_bounds__(256) void gather_agg_kernel(
    const _Float16* __restrict__ T, const int* __restrict__ row_ptr,
    const int* __restrict__ edge_src, const float* __restrict__ norm_dst,
    const float* __restrict__ bias, void* __restrict__ outv, int n) {
    constexpr int TPN = FEAT / 8;
    constexpr int NPB = 256 / TPN;
    const int node = blockIdx.x * NPB + threadIdx.x / TPN;
    const int f8 = threadIdx.x % TPN;
    if (node >= n) return;
    const int beg = row_ptr[node];
    const int end = row_ptr[node + 1];
    const h8* T8 = (const h8*)T;

    f8v acc = (f8v)0.0f;
    int j = beg;
    for (; j + 3 < end; j += 4) {
        const int s0 = edge_src[j + 0];
        const int s1 = edge_src[j + 1];
        const int s2 = edge_src[j + 2];
        const int s3 = edge_src[j + 3];
        const h8 a0 = T8[(size_t)s0 * TPN + f8];
        const h8 a1 = T8[(size_t)s1 * TPN + f8];
        const h8 a2 = T8[(size_t)s2 * TPN + f8];
        const h8 a3 = T8[(size_t)s3 * TPN + f8];
        acc += __builtin_convertvector(a0, f8v);
        acc += __builtin_convertvector(a1, f8v);
        acc += __builtin_convertvector(a2, f8v);
        acc += __builtin_convertvector(a3, f8v);
    }
    for (; j < end; ++j) {
        const int s = edge_src[j];
        acc += __builtin_convertvector(T8[(size_t)s * TPN + f8], f8v);
    }

    const float nd = norm_dst[node];
    float r[8];
#pragma unroll
    for (int k = 0; k < 8; ++k) {
        r[k] = acc[k] * nd + bias[f8 * 8 + k];
        if constexpr (RELU) r[k] = fmaxf(r[k], 0.0f);
    }

    if constexpr (OUT_HALF) {
        _Float16* out = (_Float16*)outv;
        h8 o;
#pragma unroll
        for (int k = 0; k < 8; ++k) o[k] = (_Float16)r[k];
        *(h8*)&out[(size_t)node * FEAT + f8 * 8] = o;
    } else {
        float* out = (float*)outv;
        float4 o0 = make_float4(r[0], r[1], r[2], r[3]);
        float4 o1 = make_float4(r[4], r[5], r[6], r[7]);
        *(float4*)&out[(size_t)node * FEAT + f8 * 8] = o0;
        *(float4*)&out[(size_t)node * FEAT + f8 * 8 + 4] = o1;
    }
}

extern "C" void kernel_launch(void* const* d_in, const int* in_sizes, int n_in,
                              void* d_out, int out_size, void* d_ws, size_t ws_size,
                              hipStream_t stream) {
    const float* x   = (const float*)d_in[0];   // [N,128]
    const int*   src = (const int*)d_in[1];     // [E]
    const int*   dst = (const int*)d_in[2];     // [E]
    const float* W1  = (const float*)d_in[3];   // [128,128]
    const float* b1  = (const float*)d_in[4];   // [128]
    const float* W2  = (const float*)d_in[5];   // [128,64]
    const float* b2  = (const float*)d_in[6];   // [64]
    float* out = (float*)d_out;

    const int N = in_sizes[0] / N_FEATS_IN;     // 100000
    const int E = in_sizes[1];                  // 1600000
    const int NB = (N + BK_SIZE - 1) / BK_SIZE; // 391 buckets
    const int NBLK = (E + EPB - 1) / EPB;       // 391 edge blocks

    auto align4 = [](size_t w) { return (w + 3) & ~(size_t)3; };
    char* base = (char*)d_ws;
    size_t off = 0;
    auto take = [&](size_t words) {
        char* p = base + off * 4;
        off = align4(off + words);
        return p;
    };
    unsigned int* deg_pk = (unsigned int*)take((size_t)(N + 1) / 2 + 1);
    int*   tot      = (int*)take(NB);
    int*   gb_off   = (int*)take(NB + 1);
    int*   blk_hist = (int*)take((size_t)NBLK * NB);
    uint2* ebuf     = (uint2*)take((size_t)2 * E);
    int*   row_ptr  = (int*)take(N + 1);
    int*   edge_src = (int*)take(E);
    float* norms    = (float*)take(2 * (size_t)N);
    _Float16* t1    = (_Float16*)take((size_t)N * 64);  // N x 128 fp16
    _Float16* h1    = (_Float16*)take((size_t)N * 64);  // N x 128 fp16
    _Float16* t2    = (_Float16*)take((size_t)N * 32);  // N x 64  fp16
    float* norm_src = norms;
    float* norm_dst = norms + N;

    hipMemsetAsync(deg_pk, 0, ((size_t)(N + 1) / 2 + 1) * sizeof(unsigned int),
                   stream);

    // ---- CSR build (counting sort by dst, LDS histograms) ----
    hist_kernel<<<NBLK, 256, 0, stream>>>(src, dst, blk_hist, deg_pk, E, NB);
    norm_src_kernel<<<(N + 255) / 256, 256, 0, stream>>>(deg_pk, norm_src, N);
    colsum_kernel<<<NB, 256, 0, stream>>>(blk_hist, tot, NBLK, NB);
    bscan_kernel<<<1, 256, 0, stream>>>(tot, gb_off, row_ptr, NB, N, E);
    colscan_kernel<<<NB, 256, 0, stream>>>(blk_hist, gb_off, NBLK, NB);
    scatter_kernel<<<NBLK, 256, 0, stream>>>(src, dst, blk_hist, ebuf, E, NB);
    bucket_csr_kernel<<<NB, 256, 0, stream>>>(ebuf, gb_off, row_ptr, norm_dst,
                                              edge_src, N);

    // ---- layer 1 ----
    mfma_gemm_kernel<128, false><<<(N + 127) / 128, 256, 0, stream>>>(
        x, W1, norm_src, t1, N);
    gather_agg_kernel<128, true, true><<<(N + 15) / 16, 256, 0, stream>>>(
        t1, row_ptr, edge_src, norm_dst, b1, h1, N);

    // ---- layer 2 ----
    mfma_gemm_kernel<64, true><<<(N + 127) / 128, 256, 0, stream>>>(
        h1, W2, norm_src, t2, N);
    gather_agg_kernel<64, false, false><<<(N + 31) / 32, 256, 0, stream>>>(
        t2, row_ptr, edge_src, norm_dst, b2, out, N);
}

// Round 7
// 343.133 us; speedup vs baseline: 13.0800x; 1.1345x over previous
//
#include <hip/hip_runtime.h>
#include <hip/hip_bf16.h>

#define N_FEATS_IN 128
#define BK_BITS 8
#define BK_SIZE 256      // nodes per bucket
#define EPB 4096         // edges per histogram/scatter block
#define MAXNB 512        // max buckets (N <= 131072)

typedef _Float16 h8 __attribute__((ext_vector_type(8)));
typedef float    f4v __attribute__((ext_vector_type(4)));
typedef float    f8v __attribute__((ext_vector_type(8)));

// ---------------------------------------------------------------------------
// scan / reduce helpers
// ---------------------------------------------------------------------------
__device__ inline int wave_incl_scan(int v) {
    const int lane = threadIdx.x & 63;
    for (int off = 1; off < 64; off <<= 1) {
        int u = __shfl_up(v, off, 64);
        if (lane >= off) v += u;
    }
    return v;
}

// 256-thread block exclusive scan; ws = LDS int[4]; internally synced.
// Caller must __syncthreads() before calling again (ws reuse).
__device__ inline int block_excl_scan(int s, int* ws, int* total) {
    const int lane = threadIdx.x & 63, wid = threadIdx.x >> 6;
    int inc = wave_incl_scan(s);
    if (lane == 63) ws[wid] = inc;
    __syncthreads();
    int woff = 0;
#pragma unroll
    for (int w = 0; w < 4; ++w) woff += (w < wid) ? ws[w] : 0;
    if (total) *total = ws[0] + ws[1] + ws[2] + ws[3];
    return woff + inc - s;
}

// ---------------------------------------------------------------------------
// K1: per-block LDS bucket histograms of dst>>8 AND src>>8 (no global atomics)
// ---------------------------------------------------------------------------
__global__ __launch_bounds__(256) void hist_kernel(
    const int* __restrict__ src, const int* __restrict__ dst,
    int* __restrict__ bh_d, int* __restrict__ bh_s, int E, int NB) {
    __shared__ int hd[MAXNB];
    __shared__ int hs[MAXNB];
    const int t = threadIdx.x;
    for (int i = t; i < NB; i += 256) { hd[i] = 0; hs[i] = 0; }
    __syncthreads();
    const int base = blockIdx.x * EPB;
    const int end = min(base + EPB, E);
    for (int e = base + t; e < end; e += 256) {
        atomicAdd(&hd[dst[e] >> BK_BITS], 1);
        atomicAdd(&hs[src[e] >> BK_BITS], 1);
    }
    __syncthreads();
    for (int i = t; i < NB; i += 256) {
        bh_d[(size_t)blockIdx.x * NB + i] = hd[i];
        bh_s[(size_t)blockIdx.x * NB + i] = hs[i];
    }
}

// K2a: column sums of both matrices: tot_d[b], tot_s[b]
__global__ __launch_bounds__(256) void colsum2_kernel(
    const int* __restrict__ bh_d, const int* __restrict__ bh_s,
    int* __restrict__ tot_d, int* __restrict__ tot_s, int NBLK, int NB) {
    __shared__ int ws[8];
    const int b = blockIdx.x;
    const int t = threadIdx.x;
    const int lane = t & 63, wid = t >> 6;
    int sd = 0, ss = 0;
    for (int r = t; r < NBLK; r += 256) {
        sd += bh_d[(size_t)r * NB + b];
        ss += bh_s[(size_t)r * NB + b];
    }
    for (int off = 1; off < 64; off <<= 1) {
        sd += __shfl_down(sd, off, 64);
        ss += __shfl_down(ss, off, 64);
    }
    if (lane == 0) { ws[wid] = sd; ws[4 + wid] = ss; }
    __syncthreads();
    if (t == 0) tot_d[b] = ws[0] + ws[1] + ws[2] + ws[3];
    if (t == 1) tot_s[b] = ws[4] + ws[5] + ws[6] + ws[7];
}

// K2b: single block: gb_d = excl-scan(tot_d), gb_s = excl-scan(tot_s)
__global__ __launch_bounds__(256) void bscan2_kernel(
    const int* __restrict__ tot_d, const int* __restrict__ tot_s,
    int* __restrict__ gb_d, int* __restrict__ gb_s,
    int* __restrict__ row_ptr, int NB, int N, int E) {
    __shared__ int ws[4];
    const int t = threadIdx.x;
    {
        const int a = (2 * t < NB) ? tot_d[2 * t] : 0;
        const int b = (2 * t + 1 < NB) ? tot_d[2 * t + 1] : 0;
        const int excl = block_excl_scan(a + b, ws, nullptr);
        if (2 * t < NB) gb_d[2 * t] = excl;
        if (2 * t + 1 < NB) gb_d[2 * t + 1] = excl + a;
    }
    __syncthreads();
    {
        const int a = (2 * t < NB) ? tot_s[2 * t] : 0;
        const int b = (2 * t + 1 < NB) ? tot_s[2 * t + 1] : 0;
        const int excl = block_excl_scan(a + b, ws, nullptr);
        if (2 * t < NB) gb_s[2 * t] = excl;
        if (2 * t + 1 < NB) gb_s[2 * t + 1] = excl + a;
    }
    if (t == 0) { gb_d[NB] = E; gb_s[NB] = E; row_ptr[N] = E; }
}

// K2c: per column b: bh[blk][b] <- gb[b] + prefix over blk (both matrices)
__global__ __launch_bounds__(256) void colscan2_kernel(
    int* __restrict__ bh_d, int* __restrict__ bh_s,
    const int* __restrict__ gb_d, const int* __restrict__ gb_s,
    int NBLK, int NB) {
    __shared__ int ws[4];
    const int b = blockIdx.x;
    const int t = threadIdx.x;
    const int r0 = 2 * t, r1 = 2 * t + 1;
    {
        const int a = (r0 < NBLK) ? bh_d[(size_t)r0 * NB + b] : 0;
        const int c = (r1 < NBLK) ? bh_d[(size_t)r1 * NB + b] : 0;
        const int excl = block_excl_scan(a + c, ws, nullptr);
        const int base = gb_d[b];
        if (r0 < NBLK) bh_d[(size_t)r0 * NB + b] = base + excl;
        if (r1 < NBLK) bh_d[(size_t)r1 * NB + b] = base + excl + a;
    }
    __syncthreads();
    {
        const int a = (r0 < NBLK) ? bh_s[(size_t)r0 * NB + b] : 0;
        const int c = (r1 < NBLK) ? bh_s[(size_t)r1 * NB + b] : 0;
        const int excl = block_excl_scan(a + c, ws, nullptr);
        const int base = gb_s[b];
        if (r0 < NBLK) bh_s[(size_t)r0 * NB + b] = base + excl;
        if (r1 < NBLK) bh_s[(size_t)r1 * NB + b] = base + excl + a;
    }
}

// K3: dual scatter with LDS cursors:
//   ebuf[p_d] = src<<8 | (dst&255)   (dst-bucket-grouped, u32)
//   sbuf[p_s] = src&255              (src-bucket-grouped, u8)
__global__ __launch_bounds__(256) void scatter2_kernel(
    const int* __restrict__ src, const int* __restrict__ dst,
    const int* __restrict__ bh_d, const int* __restrict__ bh_s,
    unsigned int* __restrict__ ebuf, unsigned char* __restrict__ sbuf,
    int E, int NB) {
    __shared__ int cd[MAXNB];
    __shared__ int cs[MAXNB];
    const int t = threadIdx.x;
    for (int i = t; i < NB; i += 256) {
        cd[i] = bh_d[(size_t)blockIdx.x * NB + i];
        cs[i] = bh_s[(size_t)blockIdx.x * NB + i];
    }
    __syncthreads();
    const int base = blockIdx.x * EPB;
    const int end = min(base + EPB, E);
    for (int e = base + t; e < end; e += 256) {
        const int d = dst[e];
        const int s = src[e];
        const int pd = atomicAdd(&cd[d >> BK_BITS], 1);
        ebuf[pd] = ((unsigned)s << 8) | (unsigned)(d & (BK_SIZE - 1));
        const int ps = atomicAdd(&cs[s >> BK_BITS], 1);
        sbuf[ps] = (unsigned char)(s & (BK_SIZE - 1));
    }
}

// K4: per-bucket exact CSR: row_ptr, norm_dst (fused), edge_src
__global__ __launch_bounds__(256) void bucket_csr_kernel(
    const unsigned int* __restrict__ ebuf, const int* __restrict__ gb_d,
    int* __restrict__ row_ptr, float* __restrict__ norm_dst,
    int* __restrict__ edge_src, int N) {
    __shared__ int cnt[BK_SIZE];
    __shared__ int lro[BK_SIZE];
    __shared__ int ws[4];
    const int b = blockIdx.x;
    const int t = threadIdx.x;
    const int beg = gb_d[b], end = gb_d[b + 1];

    cnt[t] = 0;
    __syncthreads();
    for (int j = beg + t; j < end; j += 256)
        atomicAdd(&cnt[ebuf[j] & (BK_SIZE - 1)], 1);
    __syncthreads();

    const int v = cnt[t];
    const int excl = block_excl_scan(v, ws, nullptr);
    lro[t] = beg + excl;
    const int node = b * BK_SIZE + t;
    if (node < N) {
        row_ptr[node] = beg + excl;
        norm_dst[node] = rsqrtf(fmaxf((float)v, 1.0f));
    }
    __syncthreads();  // ensure all lro writes + scan reads done
    cnt[t] = 0;       // reuse as cursor
    __syncthreads();

    for (int j = beg + t; j < end; j += 256) {
        const unsigned int ed = ebuf[j];
        const int dl = ed & (BK_SIZE - 1);
        const int p = atomicAdd(&cnt[dl], 1);
        edge_src[lro[dl] + p] = (int)(ed >> 8);
    }
}

// K5: per-src-bucket count -> norm_src (no ordering needed, just counts)
__global__ __launch_bounds__(256) void count_src_kernel(
    const unsigned char* __restrict__ sbuf, const int* __restrict__ gb_s,
    float* __restrict__ norm_src, int N) {
    __shared__ int cnt[BK_SIZE];
    const int b = blockIdx.x;
    const int t = threadIdx.x;
    const int beg = gb_s[b], end = gb_s[b + 1];
    cnt[t] = 0;
    __syncthreads();
    for (int j = beg + t; j < end; j += 256)
        atomicAdd(&cnt[sbuf[j]], 1);
    __syncthreads();
    const int node = b * BK_SIZE + t;
    if (node < N)
        norm_src[node] = rsqrtf(fmaxf((float)cnt[t], 1.0f));
}

// ---------------------------------------------------------------------------
// MFMA GEMM: Y[n,OC] = (X[n,128] @ W[128,OC]) * scale[n], Y fp16.
// (unchanged from R6 — verified layouts)
// ---------------------------------------------------------------------------
template <int OC, bool XHALF>
__global__ __launch_bounds__(256) void mfma_gemm_kernel(
    const void* __restrict__ Xv, const float* __restrict__ W,
    const float* __restrict__ scale, _Float16* __restrict__ Y, int n) {
    constexpr int K = 128;
    constexpr int NT = OC / 16;
    constexpr int RPB = 128;
    __shared__ _Float16 Wf[NT * 4 * 64 * 8];

    const int tid = threadIdx.x;
    for (int i = tid; i < K * OC; i += 256) {
        const int k = i / OC, c = i % OC;
        const int t = c >> 4, s = k >> 5, q = (k >> 3) & 3, j = k & 7;
        Wf[(((t * 4 + s) * 4 + q) * 16 + (c & 15)) * 8 + j] = (_Float16)W[i];
    }
    __syncthreads();

    const int lane = tid & 63;
    const int wv = tid >> 6;
    const int m = lane & 15, q = lane >> 4;

#pragma unroll
    for (int it = 0; it < RPB / 64; ++it) {
        const int rbase = blockIdx.x * RPB + it * 64 + wv * 16;
        const int lrow = min(rbase + m, n - 1);

        h8 a[4];
        if constexpr (XHALF) {
            const _Float16* X = (const _Float16*)Xv;
            const _Float16* p = &X[(size_t)lrow * K + q * 8];
#pragma unroll
            for (int s = 0; s < 4; ++s) a[s] = *(const h8*)(p + s * 32);
        } else {
            const float* X = (const float*)Xv;
            const float* p = &X[(size_t)lrow * K + q * 8];
#pragma unroll
            for (int s = 0; s < 4; ++s) {
                const float4 u0 = *(const float4*)(p + s * 32);
                const float4 u1 = *(const float4*)(p + s * 32 + 4);
                h8 v;
                v[0] = (_Float16)u0.x; v[1] = (_Float16)u0.y;
                v[2] = (_Float16)u0.z; v[3] = (_Float16)u0.w;
                v[4] = (_Float16)u1.x; v[5] = (_Float16)u1.y;
                v[6] = (_Float16)u1.z; v[7] = (_Float16)u1.w;
                a[s] = v;
            }
        }

        f4v acc[NT];
#pragma unroll
        for (int t = 0; t < NT; ++t) acc[t] = (f4v)0.0f;

#pragma unroll
        for (int s = 0; s < 4; ++s) {
#pragma unroll
            for (int t = 0; t < NT; ++t) {
                const h8 b = *(const h8*)&Wf[((t * 4 + s) * 64 + lane) * 8];
                acc[t] = __builtin_amdgcn_mfma_f32_16x16x32_f16(
                    a[s], b, acc[t], 0, 0, 0);
            }
        }

#pragma unroll
        for (int r = 0; r < 4; ++r) {
            const int orow = rbase + q * 4 + r;
            if (orow < n) {
                const float sc = scale[orow];
#pragma unroll
                for (int t = 0; t < NT; ++t)
                    Y[(size_t)orow * OC + t * 16 + m] =
                        (_Float16)(acc[t][r] * sc);
            }
        }
    }
}

// ---------------------------------------------------------------------------
// pull aggregation + fused epilogue over fp16 rows; 8x edge unroll for MLP
// ---------------------------------------------------------------------------
template <int FEAT, bool RELU, bool OUT_HALF>
__global__ __launch_bounds__(256) void gather_agg_kernel(
    const _Float16* __restrict__ T, const int* __restrict__ row_ptr,
    const int* __restrict__ edge_src, const float* __restrict__ norm_dst,
    const float* __restrict__ bias, void* __restrict__ outv, int n) {
    constexpr int TPN = FEAT / 8;
    constexpr int NPB = 256 / TPN;
    const int node = blockIdx.x * NPB + threadIdx.x / TPN;
    const int f8 = threadIdx.x % TPN;
    if (node >= n) return;
    const int beg = row_ptr[node];
    const int end = row_ptr[node + 1];
    const h8* T8 = (const h8*)T;

    f8v acc = (f8v)0.0f;
    int j = beg;
    for (; j + 7 < end; j += 8) {
        int s[8];
#pragma unroll
        for (int u = 0; u < 8; ++u) s[u] = edge_src[j + u];
        h8 a[8];
#pragma unroll
        for (int u = 0; u < 8; ++u) a[u] = T8[(size_t)s[u] * TPN + f8];
#pragma unroll
        for (int u = 0; u < 8; ++u)
            acc += __builtin_convertvector(a[u], f8v);
    }
    for (; j + 3 < end; j += 4) {
        int s[4];
#pragma unroll
        for (int u = 0; u < 4; ++u) s[u] = edge_src[j + u];
        h8 a[4];
#pragma unroll
        for (int u = 0; u < 4; ++u) a[u] = T8[(size_t)s[u] * TPN + f8];
#pragma unroll
        for (int u = 0; u < 4; ++u)
            acc += __builtin_convertvector(a[u], f8v);
    }
    for (; j < end; ++j)
        acc += __builtin_convertvector(T8[(size_t)edge_src[j] * TPN + f8], f8v);

    const float nd = norm_dst[node];
    float r[8];
#pragma unroll
    for (int k = 0; k < 8; ++k) {
        r[k] = acc[k] * nd + bias[f8 * 8 + k];
        if constexpr (RELU) r[k] = fmaxf(r[k], 0.0f);
    }

    if constexpr (OUT_HALF) {
        _Float16* out = (_Float16*)outv;
        h8 o;
#pragma unroll
        for (int k = 0; k < 8; ++k) o[k] = (_Float16)r[k];
        *(h8*)&out[(size_t)node * FEAT + f8 * 8] = o;
    } else {
        float* out = (float*)outv;
        float4 o0 = make_float4(r[0], r[1], r[2], r[3]);
        float4 o1 = make_float4(r[4], r[5], r[6], r[7]);
        *(float4*)&out[(size_t)node * FEAT + f8 * 8] = o0;
        *(float4*)&out[(size_t)node * FEAT + f8 * 8 + 4] = o1;
    }
}

extern "C" void kernel_launch(void* const* d_in, const int* in_sizes, int n_in,
                              void* d_out, int out_size, void* d_ws, size_t ws_size,
                              hipStream_t stream) {
    const float* x   = (const float*)d_in[0];   // [N,128]
    const int*   src = (const int*)d_in[1];     // [E]
    const int*   dst = (const int*)d_in[2];     // [E]
    const float* W1  = (const float*)d_in[3];   // [128,128]
    const float* b1  = (const float*)d_in[4];   // [128]
    const float* W2  = (const float*)d_in[5];   // [128,64]
    const float* b2  = (const float*)d_in[6];   // [64]
    float* out = (float*)d_out;

    const int N = in_sizes[0] / N_FEATS_IN;     // 100000
    const int E = in_sizes[1];                  // 1600000
    const int NB = (N + BK_SIZE - 1) / BK_SIZE; // 391 buckets
    const int NBLK = (E + EPB - 1) / EPB;       // 391 edge blocks

    auto align4 = [](size_t w) { return (w + 3) & ~(size_t)3; };
    char* base = (char*)d_ws;
    size_t off = 0;
    auto take = [&](size_t words) {
        char* p = base + off * 4;
        off = align4(off + words);
        return p;
    };
    int*   tot_d    = (int*)take(NB);
    int*   tot_s    = (int*)take(NB);
    int*   gb_d     = (int*)take(NB + 1);
    int*   gb_s     = (int*)take(NB + 1);
    int*   bh_d     = (int*)take((size_t)NBLK * NB);
    int*   bh_s     = (int*)take((size_t)NBLK * NB);
    unsigned int*  ebuf = (unsigned int*)take(E);
    unsigned char* sbuf = (unsigned char*)take((E + 3) / 4);
    int*   row_ptr  = (int*)take(N + 1);
    int*   edge_src = (int*)take(E);
    float* norms    = (float*)take(2 * (size_t)N);
    _Float16* t1    = (_Float16*)take((size_t)N * 64);  // N x 128 fp16
    _Float16* h1    = (_Float16*)take((size_t)N * 64);  // N x 128 fp16
    _Float16* t2    = (_Float16*)take((size_t)N * 32);  // N x 64  fp16
    float* norm_src = norms;
    float* norm_dst = norms + N;

    // ---- CSR build (dual counting sort; zero global atomics) ----
    hist_kernel<<<NBLK, 256, 0, stream>>>(src, dst, bh_d, bh_s, E, NB);
    colsum2_kernel<<<NB, 256, 0, stream>>>(bh_d, bh_s, tot_d, tot_s, NBLK, NB);
    bscan2_kernel<<<1, 256, 0, stream>>>(tot_d, tot_s, gb_d, gb_s, row_ptr,
                                         NB, N, E);
    colscan2_kernel<<<NB, 256, 0, stream>>>(bh_d, bh_s, gb_d, gb_s, NBLK, NB);
    scatter2_kernel<<<NBLK, 256, 0, stream>>>(src, dst, bh_d, bh_s, ebuf, sbuf,
                                              E, NB);
    bucket_csr_kernel<<<NB, 256, 0, stream>>>(ebuf, gb_d, row_ptr, norm_dst,
                                              edge_src, N);
    count_src_kernel<<<NB, 256, 0, stream>>>(sbuf, gb_s, norm_src, N);

    // ---- layer 1 ----
    mfma_gemm_kernel<128, false><<<(N + 127) / 128, 256, 0, stream>>>(
        x, W1, norm_src, t1, N);
    gather_agg_kernel<128, true, true><<<(N + 15) / 16, 256, 0, stream>>>(
        t1, row_ptr, edge_src, norm_dst, b1, h1, N);

    // ---- layer 2 ----
    mfma_gemm_kernel<64, true><<<(N + 127) / 128, 256, 0, stream>>>(
        h1, W2, norm_src, t2, N);
    gather_agg_kernel<64, false, false><<<(N + 31) / 32, 256, 0, stream>>>(
        t2, row_ptr, edge_src, norm_dst, b2, out, N);
}